// Round 7
// baseline (268.903 us; speedup 1.0000x reference)
//
#include <hip/hip_runtime.h>

// RbfNet on MI355X — round 27: AGGREGATE-THEN-TRANSFORM restructure.
// R20-R26 evidence: gather from the 34.5MB UL table is pinned at ~2.2TB/s
// across three totally different batching schemes (plain/asm/LDS-DMA) ->
// memory-system ceiling for random 256B requests vs an L3-resident table.
// Fix by algebra, not scheduling: conv[i] = (sum_e w*x_j) @ W  (linearity).
// - Gather now reads the FEATURE table [n,64] bf16 = 3.84MB -> per-XCD-L2
//   resident; 128B/edge (half), ~200cy latency; lane=channel, 1 ushort
//   load/edge, uniform-p switch -> 2 FMA into 8 slot accumulators a0..a7.
// - Per-node GEMM [16,576]@[576,64] AFTER aggregation (same FLOPs as the
//   old UL-prep GEMM); UL tables and their 34.5MB of traffic deleted.
// - layer0 aggregates raw X (Xb16 [n,8], 0.5MB): lane=(slot,ch) cell,
//   per-lane cndmask weight select, single accumulator.
// - lin path fused as K-rows 512..575 (own features) of the GEMM weights.
// - conv2 also emits T[n,18] = ansc2 @ cW3 via a 2-MFMA tail.
// Record (4B): j(15b)<<17 | p(3b)<<14 | real<<12 | wq(12b); w0=wq*2^-12
// mantissa trick; pads (v=0) -> w0=w1=0, j=0 (safe row-0 loads).

#define CAP 48

typedef __attribute__((ext_vector_type(8))) short short8;
typedef __attribute__((ext_vector_type(4))) float f32x4;
typedef int v4i __attribute__((ext_vector_type(4)));

__device__ __forceinline__ short bf16s(float f) {   // fp32 -> bf16 RNE
  unsigned u = __float_as_uint(f);
  return (short)((u + 0x7FFF + ((u >> 16) & 1)) >> 16);
}
__device__ __forceinline__ float b2f(unsigned short s) {
  return __uint_as_float(((unsigned)s) << 16);
}
__device__ __forceinline__ unsigned pack2(float a, float b) {
  return (unsigned)(unsigned short)bf16s(a) | ((unsigned)(unsigned short)bf16s(b) << 16);
}
__device__ __forceinline__ float dec_w0(int v) {    // w0 = wq * 2^-12, pad -> 0
  return __uint_as_float(0x3F800000u | (((unsigned)v & 0xFFFu) << 11)) - 1.0f;
}
__device__ __forceinline__ float dec_sf(int v) {    // 1.0 real record, 0.0 pad
  return (float)(((unsigned)v >> 12) & 1u);
}
__device__ __forceinline__ unsigned long long rfl64(unsigned long long x) {
  unsigned lo = __builtin_amdgcn_readfirstlane((unsigned)x);
  unsigned hi = __builtin_amdgcn_readfirstlane((unsigned)(x >> 32));
  return ((unsigned long long)hi << 32) | (unsigned long long)lo;
}

// ---- record fetch into SGPRs (proven R26 pattern) ----
#define LOAD_RECS32Q(JROW, CPTR, MRAW)                                      \
  v4i q0, q1, q2, q3, q4, q5, q6, q7;                                       \
  int MRAW;                                                                 \
  asm volatile("s_load_dwordx4 %0, %9, 0x0\n\t"                             \
               "s_load_dwordx4 %1, %9, 0x10\n\t"                            \
               "s_load_dwordx4 %2, %9, 0x20\n\t"                            \
               "s_load_dwordx4 %3, %9, 0x30\n\t"                            \
               "s_load_dwordx4 %4, %9, 0x40\n\t"                            \
               "s_load_dwordx4 %5, %9, 0x50\n\t"                            \
               "s_load_dwordx4 %6, %9, 0x60\n\t"                            \
               "s_load_dwordx4 %7, %9, 0x70\n\t"                            \
               "s_load_dword %8, %10, 0x0\n\t"                              \
               "s_waitcnt lgkmcnt(0)"                                       \
               : "=&s"(q0), "=&s"(q1), "=&s"(q2), "=&s"(q3), "=&s"(q4),     \
                 "=&s"(q5), "=&s"(q6), "=&s"(q7), "=&s"(MRAW)               \
               : "s"(JROW), "s"(CPTR)                                       \
               : "memory")

#define LOAD_RECS16TQ(JROW)                                                 \
  v4i qt0, qt1, qt2, qt3;                                                   \
  asm volatile("s_load_dwordx4 %0, %4, 0x80\n\t"                            \
               "s_load_dwordx4 %1, %4, 0x90\n\t"                            \
               "s_load_dwordx4 %2, %4, 0xA0\n\t"                            \
               "s_load_dwordx4 %3, %4, 0xB0\n\t"                            \
               "s_waitcnt lgkmcnt(0)"                                       \
               : "=&s"(qt0), "=&s"(qt1), "=&s"(qt2), "=&s"(qt3)             \
               : "s"(JROW)                                                  \
               : "memory")

// constant-folded record extract (K must be a literal at expansion)
#define RECK(K) ((K) < 4 ? q0[(K) & 3] : (K) < 8 ? q1[(K) & 3] :            \
                 (K) < 12 ? q2[(K) & 3] : (K) < 16 ? q3[(K) & 3] :          \
                 (K) < 20 ? q4[(K) & 3] : (K) < 24 ? q5[(K) & 3] :          \
                 (K) < 28 ? q6[(K) & 3] : q7[(K) & 3])
#define RECT(K) ((K) < 4 ? qt0[(K) & 3] : (K) < 8 ? qt1[(K) & 3] :          \
                 (K) < 12 ? qt2[(K) & 3] : qt3[(K) & 3])

// ---------- fused: edge-bucket build | GEMM-weight prep | Xb16 prep ----------
__global__ void fill_prep(const float* __restrict__ dist,
                          const int* __restrict__ fi, const int* __restrict__ fj,
                          int* __restrict__ cnt, int* __restrict__ jw, int nE,
                          const float* __restrict__ cW0, const float* __restrict__ fW0,
                          const float* __restrict__ cW1, const float* __restrict__ fW1,
                          const float* __restrict__ cW2, const float* __restrict__ fW2,
                          const float* __restrict__ cW3,
                          short* __restrict__ W0T, short* __restrict__ W1T,
                          short* __restrict__ W2T, short* __restrict__ WT3,
                          const float* __restrict__ X,
                          unsigned short* __restrict__ Xb, int n,
                          int fillBlocks, int prepBlocks) {
  if ((int)blockIdx.x < fillBlocks) {
    int e = blockIdx.x * blockDim.x + threadIdx.x;
    if (e >= nE) return;
    int i = fi[e], j = fj[e];
    if (i == j) return;                  // centerIgnore
    float d = fminf(1.0f, fmaxf(-1.0f, dist[e]));
    float u = (d + 1.0f) * 3.5f;         // hat centers: spacing 2/7
    int p = min((int)u, 6);
    float w0 = 1.0f - (u - (float)p);
    int wq = min((int)(w0 * 4096.0f + 0.5f), 4095);
    int pos = atomicAdd(&cnt[i], 1);
    if (pos < CAP)
      jw[(size_t)i * CAP + pos] =
          (int)(((unsigned)j << 17) | ((unsigned)p << 14) | 0x1000u | (unsigned)wq);
  } else if ((int)blockIdx.x < fillBlocks + prepBlocks) {
    int idx = ((int)blockIdx.x - fillBlocks) * blockDim.x + threadIdx.x;
    if (idx < 36864) {                   // W1T [64 out][576 k]
      int o = idx / 576, k = idx - o * 576;
      float v = (k < 512) ? cW1[((size_t)(k >> 6) * 64 + (k & 63)) * 64 + o]
                          : fW1[(size_t)(k - 512) * 64 + o];
      W1T[idx] = bf16s(v);
    } else if (idx < 73728) {            // W2T
      int r = idx - 36864;
      int o = r / 576, k = r - o * 576;
      float v = (k < 512) ? cW2[((size_t)(k >> 6) * 64 + (k & 63)) * 64 + o]
                          : fW2[(size_t)(k - 512) * 64 + o];
      W2T[r] = bf16s(v);
    } else if (idx < 77824) {            // W0T [64 out][64 k]
      int r = idx - 73728;
      int o = r >> 6, k = r & 63;
      float v = 0.0f;
      if (o < 32) {                      // lin0 outputs: own-feature rows 60..63
        if (k >= 60) v = fW0[(size_t)(k - 60) * 32 + o];
      } else {                           // conv0 outputs: k = s*8+ci, ci<4
        if ((k & 7) < 4 && k < 60)
          v = cW0[((size_t)(k >> 3) * 4 + (k & 7)) * 32 + (o - 32)];
      }
      W0T[r] = bf16s(v);
    } else if (idx < 78848) {            // WT3 [16 t][64 ch]
      int r = idx - 77824;
      int t = r >> 6, ch = r & 63;
      WT3[r] = bf16s(cW3[((size_t)(t >> 1) * 64 + ch) * 2 + (t & 1)]);
    }
  } else {
    // Xb16 [n,8]: cols 0..3 = bf16(x), 4..7 = 0
    int idx = ((int)blockIdx.x - fillBlocks - prepBlocks) * blockDim.x + threadIdx.x;
    if (idx >= n * 8) return;
    int i = idx >> 3, c = idx & 7;
    float v = (c < 4) ? X[(size_t)i * 4 + c] : 0.0f;
    Xb[idx] = (unsigned short)bf16s(v);
  }
}

// ---------- layer0: aggregate X into 8 slots x 4ch + own, GEMM W0T ----------
__global__ __launch_bounds__(1024, 8) void layer0_gemm(
    const unsigned short* __restrict__ Xb,  // [n,8] bf16 (cols 4..7 zero)
    const int* __restrict__ cnt, const int* __restrict__ jw,
    const float* __restrict__ cb0, const float* __restrict__ fb0,
    const short* __restrict__ W0T,          // [64,64] bf16
    unsigned short* __restrict__ ansc0, int n) {
  __shared__ __align__(16) unsigned short sA0[16 * 72];
  const int tid = threadIdx.x;
  const int w = tid >> 6;
  const int lane = tid & 63;
  const int s_lane = lane >> 3;             // slot 0..7
  const int k_lane = lane & 7;              // ch 0..7 (4..7 are zero pads)
  const int nodeBase = blockIdx.x * 16;
  const int i = nodeBase + w;
  const bool valid = (i < n);
  const int ic = valid ? i : 0;
  const int* jrow = (const int*)rfl64((unsigned long long)(jw + (size_t)ic * CAP));
  const int* cptr = (const int*)rfl64((unsigned long long)(cnt + ic));
  LOAD_RECS32Q(jrow, cptr, mraw);
  const int m = valid ? min(mraw, CAP) : 0;
  float acc = 0.0f;
#define L0E(K, RE)                                                          \
  { int v_ = RE(K);                                                         \
    const unsigned short* rp_ = Xb + ((size_t)((unsigned)v_ >> 17) << 3);   \
    float xv_ = b2f(rp_[k_lane]);                                           \
    float w0_ = dec_w0(v_);                                                 \
    float w1_ = dec_sf(v_) - w0_;                                           \
    int p_ = (int)(((unsigned)v_ >> 14) & 7u);                              \
    float sel_ = (s_lane == p_) ? w0_ : ((s_lane == p_ + 1) ? w1_ : 0.0f);  \
    acc = fmaf(sel_, xv_, acc); }
  L0E(0, RECK) L0E(1, RECK) L0E(2, RECK) L0E(3, RECK)
  L0E(4, RECK) L0E(5, RECK) L0E(6, RECK) L0E(7, RECK)
  L0E(8, RECK) L0E(9, RECK) L0E(10, RECK) L0E(11, RECK)
  L0E(12, RECK) L0E(13, RECK) L0E(14, RECK) L0E(15, RECK)
  if (m > 16) {
    L0E(16, RECK) L0E(17, RECK) L0E(18, RECK) L0E(19, RECK)
    L0E(20, RECK) L0E(21, RECK) L0E(22, RECK) L0E(23, RECK)
    L0E(24, RECK) L0E(25, RECK) L0E(26, RECK) L0E(27, RECK)
    L0E(28, RECK) L0E(29, RECK) L0E(30, RECK) L0E(31, RECK)
    if (m > 32) {
      LOAD_RECS16TQ(jrow);
      L0E(0, RECT) L0E(1, RECT) L0E(2, RECT) L0E(3, RECT)
      L0E(4, RECT) L0E(5, RECT) L0E(6, RECT) L0E(7, RECT)
      L0E(8, RECT) L0E(9, RECT) L0E(10, RECT) L0E(11, RECT)
      L0E(12, RECT) L0E(13, RECT) L0E(14, RECT) L0E(15, RECT)
    }
  }
#undef L0E
  float aout = acc;
  if (lane >= 60) aout = b2f(Xb[(size_t)ic * 8 + (lane - 60)]);  // own x
  sA0[w * 72 + lane] = (unsigned short)bf16s(aout);
  __syncthreads();
  if (w < 4) {                              // GEMM [16,64]@[64,64], tile t=w
    const int mrow = lane & 15, quad = lane >> 4, t = w;
    short8 b0 = *(const short8*)(sA0 + mrow * 72 + quad * 8);
    short8 b1 = *(const short8*)(sA0 + mrow * 72 + quad * 8 + 32);
    short8 a0 = *(const short8*)(W0T + (size_t)(t * 16 + mrow) * 64 + quad * 8);
    short8 a1 = *(const short8*)(W0T + (size_t)(t * 16 + mrow) * 64 + quad * 8 + 32);
    f32x4 acc4 = {0, 0, 0, 0};
    acc4 = __builtin_amdgcn_mfma_f32_16x16x32_bf16(a0, b0, acc4, 0, 0, 0);
    acc4 = __builtin_amdgcn_mfma_f32_16x16x32_bf16(a1, b1, acc4, 0, 0, 0);
    const int node2 = nodeBase + mrow;
    const int ch0 = t * 16 + quad * 4;
    if (node2 < n) {
      float vv[4];
      #pragma unroll
      for (int r = 0; r < 4; ++r) {
        int ch = ch0 + r;
        float bias = (ch < 32) ? fb0[ch] : cb0[ch - 32];
        vv[r] = fmaxf(acc4[r] + bias, 0.0f);
      }
      *(uint2*)(ansc0 + (size_t)node2 * 64 + ch0) =
          make_uint2(pack2(vv[0], vv[1]), pack2(vv[2], vv[3]));
    }
  }
}

// ---------- conv layer: aggregate feature table into 8 slots, GEMM WTn ----------
// flags: bit0 = add resid (fp32), bit1 = write fp32 out, bit2 = T pass
__global__ __launch_bounds__(1024, 8) void conv_agg(
    const unsigned short* __restrict__ ancPrev,  // [n,64] bf16 (L2-resident)
    const int* __restrict__ cnt, const int* __restrict__ jw,
    const short* __restrict__ WTn,               // [64,576] bf16
    const float* __restrict__ cb, const float* __restrict__ fb,
    const float* __restrict__ resid,             // ans1 fp32 (flags&1)
    float* __restrict__ outF32,                  // ans1 fp32 (flags&2)
    unsigned short* __restrict__ outAnsc,        // [n,64] bf16
    const short* __restrict__ WT3,               // [16,64] bf16 (flags&4)
    float* __restrict__ T, int flags, int n) {   // [n,18] fp32 (flags&4)
  __shared__ __align__(16) unsigned short sA[16 * 584];
  __shared__ __align__(16) unsigned short sC[16 * 72];
  const int tid = threadIdx.x;
  const int w = tid >> 6;
  const int lane = tid & 63;
  const int nodeBase = blockIdx.x * 16;
  const int i = nodeBase + w;
  const bool valid = (i < n);
  const int ic = valid ? i : 0;
  const int* jrow = (const int*)rfl64((unsigned long long)(jw + (size_t)ic * CAP));
  const int* cptr = (const int*)rfl64((unsigned long long)(cnt + ic));
  LOAD_RECS32Q(jrow, cptr, mraw);
  const int m = valid ? min(mraw, CAP) : 0;
  const unsigned short own = ancPrev[(size_t)ic * 64 + lane];  // own features
  float a0 = 0, a1 = 0, a2 = 0, a3 = 0, a4 = 0, a5 = 0, a6 = 0, a7 = 0;
#define CVE(K, RE)                                                          \
  { int v_ = RE(K);                                                         \
    const unsigned short* rp_ = ancPrev + ((size_t)((unsigned)v_ >> 17) << 6); \
    float xv_ = b2f(rp_[lane]);                                             \
    float w0_ = dec_w0(v_);                                                 \
    float w1_ = dec_sf(v_) - w0_;                                           \
    switch (((unsigned)v_ >> 14) & 7u) {                                    \
      case 0: a0 = fmaf(w0_, xv_, a0); a1 = fmaf(w1_, xv_, a1); break;      \
      case 1: a1 = fmaf(w0_, xv_, a1); a2 = fmaf(w1_, xv_, a2); break;      \
      case 2: a2 = fmaf(w0_, xv_, a2); a3 = fmaf(w1_, xv_, a3); break;      \
      case 3: a3 = fmaf(w0_, xv_, a3); a4 = fmaf(w1_, xv_, a4); break;      \
      case 4: a4 = fmaf(w0_, xv_, a4); a5 = fmaf(w1_, xv_, a5); break;      \
      case 5: a5 = fmaf(w0_, xv_, a5); a6 = fmaf(w1_, xv_, a6); break;      \
      case 6: a6 = fmaf(w0_, xv_, a6); a7 = fmaf(w1_, xv_, a7); break;      \
      default: break;                                                       \
    } }
  CVE(0, RECK) CVE(1, RECK) CVE(2, RECK) CVE(3, RECK)
  CVE(4, RECK) CVE(5, RECK) CVE(6, RECK) CVE(7, RECK)
  CVE(8, RECK) CVE(9, RECK) CVE(10, RECK) CVE(11, RECK)
  CVE(12, RECK) CVE(13, RECK) CVE(14, RECK) CVE(15, RECK)
  if (m > 16) {
    CVE(16, RECK) CVE(17, RECK) CVE(18, RECK) CVE(19, RECK)
    CVE(20, RECK) CVE(21, RECK) CVE(22, RECK) CVE(23, RECK)
    CVE(24, RECK) CVE(25, RECK) CVE(26, RECK) CVE(27, RECK)
    CVE(28, RECK) CVE(29, RECK) CVE(30, RECK) CVE(31, RECK)
    if (m > 32) {
      LOAD_RECS16TQ(jrow);
      CVE(0, RECT) CVE(1, RECT) CVE(2, RECT) CVE(3, RECT)
      CVE(4, RECT) CVE(5, RECT) CVE(6, RECT) CVE(7, RECT)
      CVE(8, RECT) CVE(9, RECT) CVE(10, RECT) CVE(11, RECT)
      CVE(12, RECT) CVE(13, RECT) CVE(14, RECT) CVE(15, RECT)
    }
  }
#undef CVE
  {
    unsigned short* sAr = sA + w * 584;     // K layout: s*64+ch, own at 512+ch
    sAr[0 * 64 + lane] = (unsigned short)bf16s(a0);
    sAr[1 * 64 + lane] = (unsigned short)bf16s(a1);
    sAr[2 * 64 + lane] = (unsigned short)bf16s(a2);
    sAr[3 * 64 + lane] = (unsigned short)bf16s(a3);
    sAr[4 * 64 + lane] = (unsigned short)bf16s(a4);
    sAr[5 * 64 + lane] = (unsigned short)bf16s(a5);
    sAr[6 * 64 + lane] = (unsigned short)bf16s(a6);
    sAr[7 * 64 + lane] = (unsigned short)bf16s(a7);
    sAr[512 + lane] = own;
  }
  __syncthreads();
  if (w < 4) {                              // GEMM [16,576]@[576,64], tile t=w
    const int mrow = lane & 15, quad = lane >> 4, t = w;
    f32x4 acc4 = {0, 0, 0, 0};
    const short* arow = WTn + (size_t)(t * 16 + mrow) * 576 + quad * 8;
    const unsigned short* brow = sA + mrow * 584 + quad * 8;
    #pragma unroll
    for (int kk = 0; kk < 18; ++kk) {
      short8 af = *(const short8*)(arow + kk * 32);
      short8 bf = *(const short8*)(brow + kk * 32);
      acc4 = __builtin_amdgcn_mfma_f32_16x16x32_bf16(af, bf, acc4, 0, 0, 0);
    }
    const int node2 = nodeBase + mrow;
    const int ch0 = t * 16 + quad * 4;
    if (node2 < n) {
      float4 rv = make_float4(0.f, 0.f, 0.f, 0.f);
      if (flags & 1) rv = *(const float4*)(resid + (size_t)node2 * 64 + ch0);
      float v0 = acc4[0] + cb[ch0 + 0] + fb[ch0 + 0] + rv.x;
      float v1 = acc4[1] + cb[ch0 + 1] + fb[ch0 + 1] + rv.y;
      float v2 = acc4[2] + cb[ch0 + 2] + fb[ch0 + 2] + rv.z;
      float v3 = acc4[3] + cb[ch0 + 3] + fb[ch0 + 3] + rv.w;
      if (flags & 2) {
        *(float2*)(outF32 + (size_t)node2 * 64 + ch0) = make_float2(v0, v1);
        *(float2*)(outF32 + (size_t)node2 * 64 + ch0 + 2) = make_float2(v2, v3);
      }
      unsigned lo = pack2(fmaxf(v0, 0.f), fmaxf(v1, 0.f));
      unsigned hi = pack2(fmaxf(v2, 0.f), fmaxf(v3, 0.f));
      *(uint2*)(outAnsc + (size_t)node2 * 64 + ch0) = make_uint2(lo, hi);
      if (flags & 4) {
        *(unsigned*)(sC + mrow * 72 + ch0) = lo;
        *(unsigned*)(sC + mrow * 72 + ch0 + 2) = hi;
      }
    } else if (flags & 4) {
      *(unsigned*)(sC + mrow * 72 + ch0) = 0u;
      *(unsigned*)(sC + mrow * 72 + ch0 + 2) = 0u;
    }
  }
  if (flags & 4) {                          // T[n,16] = ansc2 @ cW3 (as [64,16])
    __syncthreads();
    if (w == 0) {
      const int mrow = lane & 15, quad = lane >> 4;
      short8 b0 = *(const short8*)(sC + mrow * 72 + quad * 8);
      short8 b1 = *(const short8*)(sC + mrow * 72 + quad * 8 + 32);
      short8 a0v = *(const short8*)(WT3 + mrow * 64 + quad * 8);
      short8 a1v = *(const short8*)(WT3 + mrow * 64 + quad * 8 + 32);
      f32x4 acc4 = {0, 0, 0, 0};
      acc4 = __builtin_amdgcn_mfma_f32_16x16x32_bf16(a0v, b0, acc4, 0, 0, 0);
      acc4 = __builtin_amdgcn_mfma_f32_16x16x32_bf16(a1v, b1, acc4, 0, 0, 0);
      const int node2 = nodeBase + mrow;
      if (node2 < n) {
        float* tr = T + (size_t)node2 * 18 + quad * 4;
        *(float2*)(tr) = make_float2(acc4[0], acc4[1]);
        *(float2*)(tr + 2) = make_float2(acc4[2], acc4[3]);
      }
    }
  }
}

// ---------- layer 3: wave per node, lane = edge; 16B/edge from T; + lin ----------
__global__ __launch_bounds__(256, 4) void layer3_kernel(
    const unsigned short* __restrict__ Xb,  // ansc2 [n,64] bf16
    const float* __restrict__ T,            // [n,18] fp32 (L2-resident)
    const int* __restrict__ cnt, const int* __restrict__ jw,
    const float* __restrict__ cb3, const float* __restrict__ fb3,
    const float* __restrict__ fW3,          // [64,2]
    float* __restrict__ out, int n) {
  const int lane = threadIdx.x & 63;
  const int i = (blockIdx.x * blockDim.x + threadIdx.x) >> 6;
  if (i >= n) return;
  const int m = min(cnt[i], CAP);
  float c0 = 0.0f, c1 = 0.0f;
  if (lane < m) {                      // lane = edge index (real records only)
    int v = jw[(size_t)i * CAP + lane];
    unsigned j = (unsigned)v >> 17;
    unsigned p = ((unsigned)v >> 14) & 7u;
    unsigned off9 = j * 9u + p;        // T row = 18 floats = 9 x 8B slots
    float w0 = dec_w0(v);
    float w1 = 1.0f - w0;
    const float* tb = T + (size_t)off9 * 2;
    float2 ta = *(const float2*)(tb);
    float2 tc = *(const float2*)(tb + 2);
    c0 = w0 * ta.x + w1 * tc.x;
    c1 = w0 * ta.y + w1 * tc.y;
  }
  float xi = b2f(Xb[(size_t)i * 64 + lane]);
  float2 fw = *(const float2*)(fW3 + lane * 2);
  c0 = fmaf(xi, fw.x, c0);
  c1 = fmaf(xi, fw.y, c1);
  #pragma unroll
  for (int off = 32; off > 0; off >>= 1) {
    c0 += __shfl_xor(c0, off, 64);
    c1 += __shfl_xor(c1, off, 64);
  }
  if (lane == 0) {
    out[(size_t)i * 2 + 0] = c0 + cb3[0] + fb3[0];
    out[(size_t)i * 2 + 1] = c1 + cb3[1] + fb3[1];
  }
}

extern "C" void kernel_launch(void* const* d_in, const int* in_sizes, int n_in,
                              void* d_out, int out_size, void* d_ws, size_t ws_size,
                              hipStream_t stream) {
  const float* X    = (const float*)d_in[0];
  const int*   fi   = (const int*)d_in[1];
  const int*   fj   = (const int*)d_in[2];
  const float* dist = (const float*)d_in[3];
  const float* cW0 = (const float*)d_in[4];  const float* cb0 = (const float*)d_in[5];
  const float* fW0 = (const float*)d_in[6];  const float* fb0 = (const float*)d_in[7];
  const float* cW1 = (const float*)d_in[8];  const float* cb1 = (const float*)d_in[9];
  const float* fW1 = (const float*)d_in[10]; const float* fb1 = (const float*)d_in[11];
  const float* cW2 = (const float*)d_in[12]; const float* cb2 = (const float*)d_in[13];
  const float* fW2 = (const float*)d_in[14]; const float* fb2 = (const float*)d_in[15];
  const float* cW3 = (const float*)d_in[16]; const float* cb3 = (const float*)d_in[17];
  const float* fW3 = (const float*)d_in[18]; const float* fb3 = (const float*)d_in[19];
  float* out = (float*)d_out;

  const int n  = in_sizes[0] / 4;  // N = 30000
  const int nE = in_sizes[1];      // E = 480000

  // workspace (~28 MB):
  // ansc0 bf16[n*64] | ans1 f32[n*64] | ansc1 bf16[n*64] | ansc2 bf16[n*64]
  // | T f32[n*18] | Xb16 u16[n*8] | W1T | W2T | W0T | WT3 | jw[n*CAP] | cnt[n]
  unsigned short* ansc0 = (unsigned short*)d_ws;
  float*          ans1  = (float*)(ansc0 + (size_t)n * 64);
  unsigned short* ansc1 = (unsigned short*)(ans1 + (size_t)n * 64);
  unsigned short* ansc2 = ansc1 + (size_t)n * 64;
  float*          T     = (float*)(ansc2 + (size_t)n * 64);
  unsigned short* Xb16  = (unsigned short*)(T + (size_t)n * 18);
  short* W1T = (short*)(Xb16 + (size_t)n * 8);
  short* W2T = W1T + 36864;
  short* W0T = W2T + 36864;
  short* WT3 = W0T + 4096;
  int*   jw  = (int*)(WT3 + 1024);
  int*   cnt = jw + (size_t)n * CAP;

  hipMemsetAsync(jw, 0, ((size_t)n * CAP + n) * sizeof(int), stream);
  const int fillBlocks = (nE + 255) / 256;
  const int prepBlocks = (78848 + 255) / 256;
  const int xbBlocks   = (n * 8 + 255) / 256;
  fill_prep<<<fillBlocks + prepBlocks + xbBlocks, 256, 0, stream>>>(
      dist, fi, fj, cnt, jw, nE, cW0, fW0, cW1, fW1, cW2, fW2, cW3,
      W0T, W1T, W2T, WT3, X, Xb16, n, fillBlocks, prepBlocks);

  const int nodeBlocks = (n + 15) / 16;
  // layer0: aggregate X -> ansc0
  layer0_gemm<<<nodeBlocks, 1024, 0, stream>>>(Xb16, cnt, jw, cb0, fb0,
                                               W0T, ansc0, n);
  // conv1: ansc0 -> ans1 (fp32) + ansc1
  conv_agg<<<nodeBlocks, 1024, 0, stream>>>(ansc0, cnt, jw, W1T, cb1, fb1,
                                            ans1 /*unused resid*/, ans1, ansc1,
                                            WT3, T, /*flags=*/2, n);
  // conv2: ansc1 (+ans1 resid) -> ansc2 + T
  conv_agg<<<nodeBlocks, 1024, 0, stream>>>(ansc1, cnt, jw, W2T, cb2, fb2,
                                            ans1, ans1, ansc2,
                                            WT3, T, /*flags=*/5, n);
  // layer3
  layer3_kernel<<<(n * 64 + 255) / 256, 256, 0, stream>>>(ansc2, T, cnt, jw,
                                                          cb3, fb3, fW3, out, n);
}

// Round 8
// 258.942 us; speedup vs baseline: 1.0385x; 1.0385x over previous
//
#include <hip/hip_runtime.h>

// RbfNet on MI355X — round 28:
// R27 post-mortem: aggregate-then-transform fixed HBM (5.9% of peak) but
// conv_agg still 61us, VGPR=20 -> compiler re-serialized the per-edge gather
// loads (1 outstanding/wave, ~1100cy each; arithmetic matches measured).
// R24's scratch disaster was ARRays-as-asm-operands (allocas), not asm itself.
// This round:
// (a) 2 edges per load instruction: lanes 0-31 edge A (4B/lane = 2ch of its
//     128B row), lanes 32-63 edge B. 16 accs (8 slots x 2ch), xor32 merge.
// (b) one asm block per 16-edge batch: 8x global_load_dword tied to NAMED
//     SCALARS u0..u7 (SSA, not allocas -> real VGPRs) + waitcnt inside.
// (c) layer0 unified into conv_agg: Xb padded to [n,64], W0T as [64,576];
//     combined bias tables B0/B1/B2; one kernel, three calls.
// (d) GEMM tail: weights batched 6-at-a-time via named short8 asm loads.
// Record (4B): j(15b)<<17 | p(3b)<<14 | real<<12 | wq(12b); w0=wq*2^-12
// mantissa trick; pads (v=0) -> w0=w1=0, j=0 (safe row-0 loads).

#define CAP 48

typedef __attribute__((ext_vector_type(8))) short short8;
typedef __attribute__((ext_vector_type(4))) float f32x4;
typedef int v4i __attribute__((ext_vector_type(4)));

__device__ __forceinline__ short bf16s(float f) {   // fp32 -> bf16 RNE
  unsigned u = __float_as_uint(f);
  return (short)((u + 0x7FFF + ((u >> 16) & 1)) >> 16);
}
__device__ __forceinline__ float b2f(unsigned short s) {
  return __uint_as_float(((unsigned)s) << 16);
}
__device__ __forceinline__ unsigned pack2(float a, float b) {
  return (unsigned)(unsigned short)bf16s(a) | ((unsigned)(unsigned short)bf16s(b) << 16);
}
__device__ __forceinline__ float dec_w0(int v) {    // w0 = wq * 2^-12, pad -> 0
  return __uint_as_float(0x3F800000u | (((unsigned)v & 0xFFFu) << 11)) - 1.0f;
}
__device__ __forceinline__ float dec_sf(int v) {    // 1.0 real record, 0.0 pad
  return (float)(((unsigned)v >> 12) & 1u);
}
__device__ __forceinline__ unsigned long long rfl64(unsigned long long x) {
  unsigned lo = __builtin_amdgcn_readfirstlane((unsigned)x);
  unsigned hi = __builtin_amdgcn_readfirstlane((unsigned)(x >> 32));
  return ((unsigned long long)hi << 32) | (unsigned long long)lo;
}

// ---- record fetch into SGPRs (proven R26/R27 pattern) ----
#define LOAD_RECS32Q(JROW, CPTR, MRAW)                                      \
  v4i q0, q1, q2, q3, q4, q5, q6, q7;                                       \
  int MRAW;                                                                 \
  asm volatile("s_load_dwordx4 %0, %9, 0x0\n\t"                             \
               "s_load_dwordx4 %1, %9, 0x10\n\t"                            \
               "s_load_dwordx4 %2, %9, 0x20\n\t"                            \
               "s_load_dwordx4 %3, %9, 0x30\n\t"                            \
               "s_load_dwordx4 %4, %9, 0x40\n\t"                            \
               "s_load_dwordx4 %5, %9, 0x50\n\t"                            \
               "s_load_dwordx4 %6, %9, 0x60\n\t"                            \
               "s_load_dwordx4 %7, %9, 0x70\n\t"                            \
               "s_load_dword %8, %10, 0x0\n\t"                              \
               "s_waitcnt lgkmcnt(0)"                                       \
               : "=&s"(q0), "=&s"(q1), "=&s"(q2), "=&s"(q3), "=&s"(q4),     \
                 "=&s"(q5), "=&s"(q6), "=&s"(q7), "=&s"(MRAW)               \
               : "s"(JROW), "s"(CPTR)                                       \
               : "memory")

#define LOAD_RECS16TQ(JROW)                                                 \
  v4i qt0, qt1, qt2, qt3;                                                   \
  asm volatile("s_load_dwordx4 %0, %4, 0x80\n\t"                            \
               "s_load_dwordx4 %1, %4, 0x90\n\t"                            \
               "s_load_dwordx4 %2, %4, 0xA0\n\t"                            \
               "s_load_dwordx4 %3, %4, 0xB0\n\t"                            \
               "s_waitcnt lgkmcnt(0)"                                       \
               : "=&s"(qt0), "=&s"(qt1), "=&s"(qt2), "=&s"(qt3)             \
               : "s"(JROW)                                                  \
               : "memory")

#define RECK(K) ((K) < 4 ? q0[(K) & 3] : (K) < 8 ? q1[(K) & 3] :            \
                 (K) < 12 ? q2[(K) & 3] : (K) < 16 ? q3[(K) & 3] :          \
                 (K) < 20 ? q4[(K) & 3] : (K) < 24 ? q5[(K) & 3] :          \
                 (K) < 28 ? q6[(K) & 3] : q7[(K) & 3])
#define RECT(K) ((K) < 4 ? qt0[(K) & 3] : (K) < 8 ? qt1[(K) & 3] :          \
                 (K) < 12 ? qt2[(K) & 3] : qt3[(K) & 3])

// ---------- fused: edge-bucket build | weight/bias prep | Xb prep ----------
__global__ void fill_prep(const float* __restrict__ dist,
                          const int* __restrict__ fi, const int* __restrict__ fj,
                          int* __restrict__ cnt, int* __restrict__ jw, int nE,
                          const float* __restrict__ cW0, const float* __restrict__ fW0,
                          const float* __restrict__ cb0, const float* __restrict__ fb0,
                          const float* __restrict__ cW1, const float* __restrict__ fW1,
                          const float* __restrict__ cb1, const float* __restrict__ fb1,
                          const float* __restrict__ cW2, const float* __restrict__ fW2,
                          const float* __restrict__ cb2, const float* __restrict__ fb2,
                          const float* __restrict__ cW3,
                          short* __restrict__ W0T, short* __restrict__ W1T,
                          short* __restrict__ W2T, short* __restrict__ WT3,
                          float* __restrict__ BIA,   // [3*64] combined biases
                          const float* __restrict__ X,
                          unsigned short* __restrict__ Xb, int n,
                          int fillBlocks, int prepBlocks) {
  if ((int)blockIdx.x < fillBlocks) {
    int e = blockIdx.x * blockDim.x + threadIdx.x;
    if (e >= nE) return;
    int i = fi[e], j = fj[e];
    if (i == j) return;                  // centerIgnore
    float d = fminf(1.0f, fmaxf(-1.0f, dist[e]));
    float u = (d + 1.0f) * 3.5f;         // hat centers: spacing 2/7
    int p = min((int)u, 6);
    float w0 = 1.0f - (u - (float)p);
    int wq = min((int)(w0 * 4096.0f + 0.5f), 4095);
    int pos = atomicAdd(&cnt[i], 1);
    if (pos < CAP)
      jw[(size_t)i * CAP + pos] =
          (int)(((unsigned)j << 17) | ((unsigned)p << 14) | 0x1000u | (unsigned)wq);
  } else if ((int)blockIdx.x < fillBlocks + prepBlocks) {
    int idx = ((int)blockIdx.x - fillBlocks) * blockDim.x + threadIdx.x;
    if (idx < 36864) {                   // W1T [64 out][576 k]
      int o = idx / 576, k = idx - o * 576;
      float v = (k < 512) ? cW1[((size_t)(k >> 6) * 64 + (k & 63)) * 64 + o]
                          : fW1[(size_t)(k - 512) * 64 + o];
      W1T[idx] = bf16s(v);
    } else if (idx < 73728) {            // W2T
      int r = idx - 36864;
      int o = r / 576, k = r - o * 576;
      float v = (k < 512) ? cW2[((size_t)(k >> 6) * 64 + (k & 63)) * 64 + o]
                          : fW2[(size_t)(k - 512) * 64 + o];
      W2T[r] = bf16s(v);
    } else if (idx < 110592) {           // W0T [64 out][576 k], mostly zero
      int r = idx - 73728;
      int o = r / 576, k = r - o * 576;
      float v = 0.0f;
      if (k < 512) {
        int s = k >> 6, ci = k & 63;
        if (ci < 4 && o >= 32) v = cW0[((size_t)s * 4 + ci) * 32 + (o - 32)];
      } else {
        int c = k - 512;
        if (c < 4 && o < 32) v = fW0[(size_t)c * 32 + o];
      }
      W0T[r] = bf16s(v);
    } else if (idx < 111616) {           // WT3 [16 t][64 ch]
      int r = idx - 110592;
      int t = r >> 6, ch = r & 63;
      WT3[r] = bf16s(cW3[((size_t)(t >> 1) * 64 + ch) * 2 + (t & 1)]);
    } else if (idx < 111808) {           // combined biases [3][64]
      int r = idx - 111616;
      int layer = r >> 6, ch = r & 63;
      float v;
      if (layer == 0) v = (ch < 32) ? fb0[ch] : cb0[ch - 32];
      else if (layer == 1) v = cb1[ch] + fb1[ch];
      else v = cb2[ch] + fb2[ch];
      BIA[r] = v;
    }
  } else {
    // Xb [n,64] bf16: cols 0..3 = x, 4..63 = 0  (uniform row size = conv path)
    int idx = ((int)blockIdx.x - fillBlocks - prepBlocks) * blockDim.x + threadIdx.x;
    if (idx >= n * 64) return;
    int i = idx >> 6, c = idx & 63;
    float v = (c < 4) ? X[(size_t)i * 4 + c] : 0.0f;
    Xb[idx] = (unsigned short)bf16s(v);
  }
}

// ---------- unified conv layer: batched gather-aggregate + GEMM ----------
// flags: bit0 = add resid (fp32), bit1 = write fp32 out, bit2 = T pass
__global__ __launch_bounds__(1024, 8) void conv_agg(
    const unsigned short* __restrict__ prev,     // [n,64] bf16
    const int* __restrict__ cnt, const int* __restrict__ jw,
    const short* __restrict__ WTn,               // [64,576] bf16
    const float* __restrict__ bias,              // [64] combined
    const float* __restrict__ resid,             // fp32 (flags&1)
    float* __restrict__ outF32,                  // fp32 (flags&2)
    unsigned short* __restrict__ outAnsc,        // [n,64] bf16
    const short* __restrict__ WT3,               // [16,64] bf16 (flags&4)
    float* __restrict__ T, int flags, int n) {   // [n,18] fp32 (flags&4)
  __shared__ __align__(16) unsigned short sA[16 * 584];
  __shared__ __align__(16) unsigned short sC[16 * 72];
  const int tid = threadIdx.x;
  const int w = tid >> 6;
  const int lane = tid & 63;
  const int half = lane >> 5;               // 0 -> edge A, 1 -> edge B
  const int l32 = lane & 31;
  const unsigned ln4 = (unsigned)l32 * 4u;  // 2 channels per lane (4B)
  const int nodeBase = blockIdx.x * 16;
  const int i = nodeBase + w;
  const bool valid = (i < n);
  const int ic = valid ? i : 0;
  const int* jrow = (const int*)rfl64((unsigned long long)(jw + (size_t)ic * CAP));
  const int* cptr = (const int*)rfl64((unsigned long long)(cnt + ic));
  LOAD_RECS32Q(jrow, cptr, mraw);
  const int m = valid ? min(mraw, CAP) : 0;
  const unsigned short own = prev[(size_t)ic * 64 + lane];
  // accumulators: slot s, lane's 2 channels (lo/hi) — named scalars (no allocas)
  float aL0 = 0, aL1 = 0, aL2 = 0, aL3 = 0, aL4 = 0, aL5 = 0, aL6 = 0, aL7 = 0;
  float aH0 = 0, aH1 = 0, aH2 = 0, aH3 = 0, aH4 = 0, aH5 = 0, aH6 = 0, aH7 = 0;
  unsigned u0, u1, u2, u3, u4, u5, u6, u7;
  int v0, v1, v2, v3, v4, v5, v6, v7;
#define GSET(G, EA, EB)                                                     \
  { v##G = half ? (EB) : (EA);                                              \
    u##G = ((((unsigned)v##G) >> 10) & 0xFFFFFF80u) + ln4; }
#define GISSUE8(BASE)                                                       \
  asm volatile("global_load_dword %0, %0, %[bb]\n\t"                        \
               "global_load_dword %1, %1, %[bb]\n\t"                        \
               "global_load_dword %2, %2, %[bb]\n\t"                        \
               "global_load_dword %3, %3, %[bb]\n\t"                        \
               "global_load_dword %4, %4, %[bb]\n\t"                        \
               "global_load_dword %5, %5, %[bb]\n\t"                        \
               "global_load_dword %6, %6, %[bb]\n\t"                        \
               "global_load_dword %7, %7, %[bb]\n\t"                        \
               "s_waitcnt vmcnt(0)"                                         \
               : "+v"(u0), "+v"(u1), "+v"(u2), "+v"(u3),                    \
                 "+v"(u4), "+v"(u5), "+v"(u6), "+v"(u7)                     \
               : [bb] "s"(BASE)                                             \
               : "memory")
#define SLOT1(S)                                                            \
  { float sel_ = (p_ == (S)) ? w0_ : (p_ == ((S)-1)) ? w1_ : 0.0f;          \
    aL##S = fmaf(sel_, xl_, aL##S);                                         \
    aH##S = fmaf(sel_, xh_, aH##S); }
#define GCONS(G)                                                            \
  { int vv_ = v##G;                                                         \
    unsigned uu_ = u##G;                                                    \
    float w0_ = dec_w0(vv_);                                                \
    float w1_ = dec_sf(vv_) - w0_;                                          \
    int p_ = (int)(((unsigned)vv_ >> 14) & 7u);                             \
    float xl_ = __uint_as_float(uu_ << 16);                                 \
    float xh_ = __uint_as_float(uu_ & 0xFFFF0000u);                         \
    SLOT1(0) SLOT1(1) SLOT1(2) SLOT1(3) SLOT1(4) SLOT1(5) SLOT1(6) SLOT1(7) }
  // batch 1: edges 0..15 (pads decode to weight 0)
  GSET(0, RECK(0), RECK(1))   GSET(1, RECK(2), RECK(3))
  GSET(2, RECK(4), RECK(5))   GSET(3, RECK(6), RECK(7))
  GSET(4, RECK(8), RECK(9))   GSET(5, RECK(10), RECK(11))
  GSET(6, RECK(12), RECK(13)) GSET(7, RECK(14), RECK(15))
  GISSUE8(prev);
  GCONS(0) GCONS(1) GCONS(2) GCONS(3) GCONS(4) GCONS(5) GCONS(6) GCONS(7)
  if (m > 16) {                              // batch 2: edges 16..31
    GSET(0, RECK(16), RECK(17)) GSET(1, RECK(18), RECK(19))
    GSET(2, RECK(20), RECK(21)) GSET(3, RECK(22), RECK(23))
    GSET(4, RECK(24), RECK(25)) GSET(5, RECK(26), RECK(27))
    GSET(6, RECK(28), RECK(29)) GSET(7, RECK(30), RECK(31))
    GISSUE8(prev);
    GCONS(0) GCONS(1) GCONS(2) GCONS(3) GCONS(4) GCONS(5) GCONS(6) GCONS(7)
    if (m > 32) {                            // batch 3: edges 32..47 (rare)
      LOAD_RECS16TQ(jrow);
      GSET(0, RECT(0), RECT(1))   GSET(1, RECT(2), RECT(3))
      GSET(2, RECT(4), RECT(5))   GSET(3, RECT(6), RECT(7))
      GSET(4, RECT(8), RECT(9))   GSET(5, RECT(10), RECT(11))
      GSET(6, RECT(12), RECT(13)) GSET(7, RECT(14), RECT(15))
      GISSUE8(prev);
      GCONS(0) GCONS(1) GCONS(2) GCONS(3) GCONS(4) GCONS(5) GCONS(6) GCONS(7)
    }
  }
#undef GSET
#undef GISSUE8
#undef SLOT1
#undef GCONS
  // merge edge-A/edge-B halves
#define RED(S)                                                              \
  aL##S += __shfl_xor(aL##S, 32, 64);                                       \
  aH##S += __shfl_xor(aH##S, 32, 64);
  RED(0) RED(1) RED(2) RED(3) RED(4) RED(5) RED(6) RED(7)
#undef RED
  unsigned short* sAr = sA + w * 584;        // K layout: s*64+ch, own at 512+ch
  if (half == 0) {                           // lane l32 owns channels 2l32,2l32+1
#define SWR(S) ((unsigned*)(sAr + (S)*64))[l32] = pack2(aL##S, aH##S);
    SWR(0) SWR(1) SWR(2) SWR(3) SWR(4) SWR(5) SWR(6) SWR(7)
#undef SWR
  }
  sAr[512 + lane] = own;
  __syncthreads();

  if (w < 4) {                               // GEMM [16,576]@[576,64], tile t=w
    const int mrow = lane & 15, quad = lane >> 4, t = w;
    const unsigned rowoff = (unsigned)((t * 16 + mrow) * 1152 + quad * 16);
    const unsigned short* brow = sA + mrow * 584 + quad * 8;
    f32x4 acc4 = {0, 0, 0, 0};
    short8 f0, f1, f2, f3, f4, f5;
#define WLOAD6(CO)                                                          \
  asm volatile("global_load_dwordx4 %0, %[vo], %[bb] offset:0\n\t"          \
               "global_load_dwordx4 %1, %[vo], %[bb] offset:64\n\t"         \
               "global_load_dwordx4 %2, %[vo], %[bb] offset:128\n\t"        \
               "global_load_dwordx4 %3, %[vo], %[bb] offset:192\n\t"        \
               "global_load_dwordx4 %4, %[vo], %[bb] offset:256\n\t"        \
               "global_load_dwordx4 %5, %[vo], %[bb] offset:320\n\t"        \
               "s_waitcnt vmcnt(0)"                                         \
               : "=&v"(f0), "=&v"(f1), "=&v"(f2), "=&v"(f3),                \
                 "=&v"(f4), "=&v"(f5)                                       \
               : [vo] "v"(rowoff + (CO)), [bb] "s"(WTn)                     \
               : "memory")
#define MM6(KK0)                                                            \
  acc4 = __builtin_amdgcn_mfma_f32_16x16x32_bf16(                           \
      f0, *(const short8*)(brow + ((KK0) + 0) * 32), acc4, 0, 0, 0);        \
  acc4 = __builtin_amdgcn_mfma_f32_16x16x32_bf16(                           \
      f1, *(const short8*)(brow + ((KK0) + 1) * 32), acc4, 0, 0, 0);        \
  acc4 = __builtin_amdgcn_mfma_f32_16x16x32_bf16(                           \
      f2, *(const short8*)(brow + ((KK0) + 2) * 32), acc4, 0, 0, 0);        \
  acc4 = __builtin_amdgcn_mfma_f32_16x16x32_bf16(                           \
      f3, *(const short8*)(brow + ((KK0) + 3) * 32), acc4, 0, 0, 0);        \
  acc4 = __builtin_amdgcn_mfma_f32_16x16x32_bf16(                           \
      f4, *(const short8*)(brow + ((KK0) + 4) * 32), acc4, 0, 0, 0);        \
  acc4 = __builtin_amdgcn_mfma_f32_16x16x32_bf16(                           \
      f5, *(const short8*)(brow + ((KK0) + 5) * 32), acc4, 0, 0, 0);
    WLOAD6(0);    MM6(0);
    WLOAD6(384);  MM6(6);
    WLOAD6(768);  MM6(12);
#undef WLOAD6
#undef MM6
    const int node2 = nodeBase + mrow;
    const int ch0 = t * 16 + quad * 4;
    if (node2 < n) {
      float4 bb4 = *(const float4*)(bias + ch0);
      float4 rv = make_float4(0.f, 0.f, 0.f, 0.f);
      if (flags & 1) rv = *(const float4*)(resid + (size_t)node2 * 64 + ch0);
      float o0 = acc4[0] + bb4.x + rv.x;
      float o1 = acc4[1] + bb4.y + rv.y;
      float o2 = acc4[2] + bb4.z + rv.z;
      float o3 = acc4[3] + bb4.w + rv.w;
      if (flags & 2) {
        *(float2*)(outF32 + (size_t)node2 * 64 + ch0) = make_float2(o0, o1);
        *(float2*)(outF32 + (size_t)node2 * 64 + ch0 + 2) = make_float2(o2, o3);
      }
      unsigned lo = pack2(fmaxf(o0, 0.f), fmaxf(o1, 0.f));
      unsigned hi = pack2(fmaxf(o2, 0.f), fmaxf(o3, 0.f));
      *(uint2*)(outAnsc + (size_t)node2 * 64 + ch0) = make_uint2(lo, hi);
      if (flags & 4) {
        *(unsigned*)(sC + mrow * 72 + ch0) = lo;
        *(unsigned*)(sC + mrow * 72 + ch0 + 2) = hi;
      }
    } else if (flags & 4) {
      *(unsigned*)(sC + mrow * 72 + ch0) = 0u;
      *(unsigned*)(sC + mrow * 72 + ch0 + 2) = 0u;
    }
  }
  if (flags & 4) {                           // T = ansc2 @ cW3 tail
    __syncthreads();
    if (w == 0) {
      const int mrow = lane & 15, quad = lane >> 4;
      short8 b0 = *(const short8*)(sC + mrow * 72 + quad * 8);
      short8 b1 = *(const short8*)(sC + mrow * 72 + quad * 8 + 32);
      short8 a0v = *(const short8*)(WT3 + mrow * 64 + quad * 8);
      short8 a1v = *(const short8*)(WT3 + mrow * 64 + quad * 8 + 32);
      f32x4 acc4 = {0, 0, 0, 0};
      acc4 = __builtin_amdgcn_mfma_f32_16x16x32_bf16(a0v, b0, acc4, 0, 0, 0);
      acc4 = __builtin_amdgcn_mfma_f32_16x16x32_bf16(a1v, b1, acc4, 0, 0, 0);
      const int node2 = nodeBase + mrow;
      if (node2 < n) {
        float* tr = T + (size_t)node2 * 18 + quad * 4;
        *(float2*)(tr) = make_float2(acc4[0], acc4[1]);
        *(float2*)(tr + 2) = make_float2(acc4[2], acc4[3]);
      }
    }
  }
}

// ---------- layer 3: wave per node, lane = edge; 16B/edge from T; + lin ----------
__global__ __launch_bounds__(256, 4) void layer3_kernel(
    const unsigned short* __restrict__ Xb,  // ansc2 [n,64] bf16
    const float* __restrict__ T,            // [n,18] fp32 (L2-resident)
    const int* __restrict__ cnt, const int* __restrict__ jw,
    const float* __restrict__ cb3, const float* __restrict__ fb3,
    const float* __restrict__ fW3,          // [64,2]
    float* __restrict__ out, int n) {
  const int lane = threadIdx.x & 63;
  const int i = (blockIdx.x * blockDim.x + threadIdx.x) >> 6;
  if (i >= n) return;
  const int m = min(cnt[i], CAP);
  float c0 = 0.0f, c1 = 0.0f;
  if (lane < m) {                      // lane = edge index (real records only)
    int v = jw[(size_t)i * CAP + lane];
    unsigned j = (unsigned)v >> 17;
    unsigned p = ((unsigned)v >> 14) & 7u;
    unsigned off9 = j * 9u + p;        // T row = 18 floats = 9 x 8B slots
    float w0 = dec_w0(v);
    float w1 = 1.0f - w0;
    const float* tb = T + (size_t)off9 * 2;
    float2 ta = *(const float2*)(tb);
    float2 tc = *(const float2*)(tb + 2);
    c0 = w0 * ta.x + w1 * tc.x;
    c1 = w0 * ta.y + w1 * tc.y;
  }
  float xi = b2f(Xb[(size_t)i * 64 + lane]);
  float2 fw = *(const float2*)(fW3 + lane * 2);
  c0 = fmaf(xi, fw.x, c0);
  c1 = fmaf(xi, fw.y, c1);
  #pragma unroll
  for (int off = 32; off > 0; off >>= 1) {
    c0 += __shfl_xor(c0, off, 64);
    c1 += __shfl_xor(c1, off, 64);
  }
  if (lane == 0) {
    out[(size_t)i * 2 + 0] = c0 + cb3[0] + fb3[0];
    out[(size_t)i * 2 + 1] = c1 + cb3[1] + fb3[1];
  }
}

extern "C" void kernel_launch(void* const* d_in, const int* in_sizes, int n_in,
                              void* d_out, int out_size, void* d_ws, size_t ws_size,
                              hipStream_t stream) {
  const float* X    = (const float*)d_in[0];
  const int*   fi   = (const int*)d_in[1];
  const int*   fj   = (const int*)d_in[2];
  const float* dist = (const float*)d_in[3];
  const float* cW0 = (const float*)d_in[4];  const float* cb0 = (const float*)d_in[5];
  const float* fW0 = (const float*)d_in[6];  const float* fb0 = (const float*)d_in[7];
  const float* cW1 = (const float*)d_in[8];  const float* cb1 = (const float*)d_in[9];
  const float* fW1 = (const float*)d_in[10]; const float* fb1 = (const float*)d_in[11];
  const float* cW2 = (const float*)d_in[12]; const float* cb2 = (const float*)d_in[13];
  const float* fW2 = (const float*)d_in[14]; const float* fb2 = (const float*)d_in[15];
  const float* cW3 = (const float*)d_in[16]; const float* cb3 = (const float*)d_in[17];
  const float* fW3 = (const float*)d_in[18]; const float* fb3 = (const float*)d_in[19];
  float* out = (float*)d_out;

  const int n  = in_sizes[0] / 4;  // N = 30000
  const int nE = in_sizes[1];      // E = 480000

  // workspace (~31 MB):
  // ansc0 bf16[n*64] | ans1 f32[n*64] | ansc1 bf16[n*64] | ansc2 bf16[n*64]
  // | T f32[n*18] | Xb u16[n*64] | W1T | W2T | W0T | WT3 | BIA | jw | cnt
  unsigned short* ansc0 = (unsigned short*)d_ws;
  float*          ans1  = (float*)(ansc0 + (size_t)n * 64);
  unsigned short* ansc1 = (unsigned short*)(ans1 + (size_t)n * 64);
  unsigned short* ansc2 = ansc1 + (size_t)n * 64;
  float*          T     = (float*)(ansc2 + (size_t)n * 64);
  unsigned short* Xb16  = (unsigned short*)(T + (size_t)n * 18);
  short* W1T = (short*)(Xb16 + (size_t)n * 64);
  short* W2T = W1T + 36864;
  short* W0T = W2T + 36864;
  short* WT3 = W0T + 36864;
  float* BIA = (float*)(WT3 + 1024);
  int*   jw  = (int*)(BIA + 192);
  int*   cnt = jw + (size_t)n * CAP;

  hipMemsetAsync(jw, 0, ((size_t)n * CAP + n) * sizeof(int), stream);
  const int fillBlocks = (nE + 255) / 256;
  const int prepBlocks = (111808 + 255) / 256;
  const int xbBlocks   = (n * 64 + 255) / 256;
  fill_prep<<<fillBlocks + prepBlocks + xbBlocks, 256, 0, stream>>>(
      dist, fi, fj, cnt, jw, nE,
      cW0, fW0, cb0, fb0, cW1, fW1, cb1, fb1, cW2, fW2, cb2, fb2, cW3,
      W0T, W1T, W2T, WT3, BIA, X, Xb16, n, fillBlocks, prepBlocks);

  const int nodeBlocks = (n + 15) / 16;
  // layer0: conv_agg on padded Xb with W0T (flags=0)
  conv_agg<<<nodeBlocks, 1024, 0, stream>>>(Xb16, cnt, jw, W0T, BIA,
                                            ans1, ans1, ansc0, WT3, T, 0, n);
  // conv1: ansc0 -> ans1 (fp32) + ansc1 (flags=2)
  conv_agg<<<nodeBlocks, 1024, 0, stream>>>(ansc0, cnt, jw, W1T, BIA + 64,
                                            ans1, ans1, ansc1, WT3, T, 2, n);
  // conv2: ansc1 (+ans1 resid) -> ansc2 + T (flags=5)
  conv_agg<<<nodeBlocks, 1024, 0, stream>>>(ansc1, cnt, jw, W2T, BIA + 128,
                                            ans1, ans1, ansc2, WT3, T, 5, n);
  // layer3
  layer3_kernel<<<(n * 64 + 255) / 256, 256, 0, stream>>>(ansc2, T, cnt, jw,
                                                          cb3, fb3, fW3, out, n);
}

// Round 9
// 249.409 us; speedup vs baseline: 1.0782x; 1.0382x over previous
//
#include <hip/hip_runtime.h>

// RbfNet on MI355X — round 29:
// R28 post-mortem: batched asm loads fixed latency (no spills, VGPR 32) but
// VALUBusy 67% -> the 2-edges-per-load pairing made records divergent and
// forced an 8-slot cndmask chain (~50 VALU/edge for 4 useful FLOPs).
// R27's consumption was lean (uniform SGPR record -> SALU switch -> 2 FMA/edge,
// VALUBusy 22%) but its loads serialized. This round combines both:
// - uniform edge per slot: lane=channel, global_load_ushort (64x2B = one
//   128B row per request, same request count as R28);
// - R28 named-scalar asm batching: u0..u15, 16 loads in one block;
// - counted-wait pipeline: vmcnt(8) in the issue block -> consume 0-7 while
//   8-15 in flight -> tied vmcnt(0) -> consume 8-15 (T4 idiom; tied "+v" on
//   u8..u15 orders the register-only FMAs after the wait, rule #18).
// - no cross-lane merges (one wave = one node's 64 channels).
// - fill_prep Xb fill vectorized (uint4, 8x fewer threads).
// Record (4B): j(15b)<<17 | p(3b)<<14 | real<<12 | wq(12b); w0=wq*2^-12
// mantissa trick; pads (v=0) -> w0=w1=0, j=0 (safe row-0 loads).

#define CAP 48

typedef __attribute__((ext_vector_type(8))) short short8;
typedef __attribute__((ext_vector_type(4))) float f32x4;
typedef int v4i __attribute__((ext_vector_type(4)));

__device__ __forceinline__ short bf16s(float f) {   // fp32 -> bf16 RNE
  unsigned u = __float_as_uint(f);
  return (short)((u + 0x7FFF + ((u >> 16) & 1)) >> 16);
}
__device__ __forceinline__ float b2f(unsigned short s) {
  return __uint_as_float(((unsigned)s) << 16);
}
__device__ __forceinline__ unsigned pack2(float a, float b) {
  return (unsigned)(unsigned short)bf16s(a) | ((unsigned)(unsigned short)bf16s(b) << 16);
}
__device__ __forceinline__ float dec_w0(int v) {    // w0 = wq * 2^-12, pad -> 0
  return __uint_as_float(0x3F800000u | (((unsigned)v & 0xFFFu) << 11)) - 1.0f;
}
__device__ __forceinline__ float dec_sf(int v) {    // 1.0 real record, 0.0 pad
  return (float)(((unsigned)v >> 12) & 1u);
}
__device__ __forceinline__ unsigned long long rfl64(unsigned long long x) {
  unsigned lo = __builtin_amdgcn_readfirstlane((unsigned)x);
  unsigned hi = __builtin_amdgcn_readfirstlane((unsigned)(x >> 32));
  return ((unsigned long long)hi << 32) | (unsigned long long)lo;
}

// ---- record fetch into SGPRs (proven R26-R28 pattern) ----
#define LOAD_RECS32Q(JROW, CPTR, MRAW)                                      \
  v4i q0, q1, q2, q3, q4, q5, q6, q7;                                       \
  int MRAW;                                                                 \
  asm volatile("s_load_dwordx4 %0, %9, 0x0\n\t"                             \
               "s_load_dwordx4 %1, %9, 0x10\n\t"                            \
               "s_load_dwordx4 %2, %9, 0x20\n\t"                            \
               "s_load_dwordx4 %3, %9, 0x30\n\t"                            \
               "s_load_dwordx4 %4, %9, 0x40\n\t"                            \
               "s_load_dwordx4 %5, %9, 0x50\n\t"                            \
               "s_load_dwordx4 %6, %9, 0x60\n\t"                            \
               "s_load_dwordx4 %7, %9, 0x70\n\t"                            \
               "s_load_dword %8, %10, 0x0\n\t"                              \
               "s_waitcnt lgkmcnt(0)"                                       \
               : "=&s"(q0), "=&s"(q1), "=&s"(q2), "=&s"(q3), "=&s"(q4),     \
                 "=&s"(q5), "=&s"(q6), "=&s"(q7), "=&s"(MRAW)               \
               : "s"(JROW), "s"(CPTR)                                       \
               : "memory")

#define LOAD_RECS16TQ(JROW)                                                 \
  v4i qt0, qt1, qt2, qt3;                                                   \
  asm volatile("s_load_dwordx4 %0, %4, 0x80\n\t"                            \
               "s_load_dwordx4 %1, %4, 0x90\n\t"                            \
               "s_load_dwordx4 %2, %4, 0xA0\n\t"                            \
               "s_load_dwordx4 %3, %4, 0xB0\n\t"                            \
               "s_waitcnt lgkmcnt(0)"                                       \
               : "=&s"(qt0), "=&s"(qt1), "=&s"(qt2), "=&s"(qt3)             \
               : "s"(JROW)                                                  \
               : "memory")

#define RECK(K) ((K) < 4 ? q0[(K) & 3] : (K) < 8 ? q1[(K) & 3] :            \
                 (K) < 12 ? q2[(K) & 3] : (K) < 16 ? q3[(K) & 3] :          \
                 (K) < 20 ? q4[(K) & 3] : (K) < 24 ? q5[(K) & 3] :          \
                 (K) < 28 ? q6[(K) & 3] : q7[(K) & 3])
#define RECT(K) ((K) < 4 ? qt0[(K) & 3] : (K) < 8 ? qt1[(K) & 3] :          \
                 (K) < 12 ? qt2[(K) & 3] : qt3[(K) & 3])

// ---------- fused: edge-bucket build | weight/bias prep | Xb prep ----------
__global__ void fill_prep(const float* __restrict__ dist,
                          const int* __restrict__ fi, const int* __restrict__ fj,
                          int* __restrict__ cnt, int* __restrict__ jw, int nE,
                          const float* __restrict__ cW0, const float* __restrict__ fW0,
                          const float* __restrict__ cb0, const float* __restrict__ fb0,
                          const float* __restrict__ cW1, const float* __restrict__ fW1,
                          const float* __restrict__ cb1, const float* __restrict__ fb1,
                          const float* __restrict__ cW2, const float* __restrict__ fW2,
                          const float* __restrict__ cb2, const float* __restrict__ fb2,
                          const float* __restrict__ cW3,
                          short* __restrict__ W0T, short* __restrict__ W1T,
                          short* __restrict__ W2T, short* __restrict__ WT3,
                          float* __restrict__ BIA,   // [3*64] combined biases
                          const float* __restrict__ X,
                          unsigned short* __restrict__ Xb, int n,
                          int fillBlocks, int prepBlocks) {
  if ((int)blockIdx.x < fillBlocks) {
    int e = blockIdx.x * blockDim.x + threadIdx.x;
    if (e >= nE) return;
    int i = fi[e], j = fj[e];
    if (i == j) return;                  // centerIgnore
    float d = fminf(1.0f, fmaxf(-1.0f, dist[e]));
    float u = (d + 1.0f) * 3.5f;         // hat centers: spacing 2/7
    int p = min((int)u, 6);
    float w0 = 1.0f - (u - (float)p);
    int wq = min((int)(w0 * 4096.0f + 0.5f), 4095);
    int pos = atomicAdd(&cnt[i], 1);
    if (pos < CAP)
      jw[(size_t)i * CAP + pos] =
          (int)(((unsigned)j << 17) | ((unsigned)p << 14) | 0x1000u | (unsigned)wq);
  } else if ((int)blockIdx.x < fillBlocks + prepBlocks) {
    int idx = ((int)blockIdx.x - fillBlocks) * blockDim.x + threadIdx.x;
    if (idx < 36864) {                   // W1T [64 out][576 k]
      int o = idx / 576, k = idx - o * 576;
      float v = (k < 512) ? cW1[((size_t)(k >> 6) * 64 + (k & 63)) * 64 + o]
                          : fW1[(size_t)(k - 512) * 64 + o];
      W1T[idx] = bf16s(v);
    } else if (idx < 73728) {            // W2T
      int r = idx - 36864;
      int o = r / 576, k = r - o * 576;
      float v = (k < 512) ? cW2[((size_t)(k >> 6) * 64 + (k & 63)) * 64 + o]
                          : fW2[(size_t)(k - 512) * 64 + o];
      W2T[r] = bf16s(v);
    } else if (idx < 110592) {           // W0T [64 out][576 k], mostly zero
      int r = idx - 73728;
      int o = r / 576, k = r - o * 576;
      float v = 0.0f;
      if (k < 512) {
        int s = k >> 6, ci = k & 63;
        if (ci < 4 && o >= 32) v = cW0[((size_t)s * 4 + ci) * 32 + (o - 32)];
      } else {
        int c = k - 512;
        if (c < 4 && o < 32) v = fW0[(size_t)c * 32 + o];
      }
      W0T[r] = bf16s(v);
    } else if (idx < 111616) {           // WT3 [16 t][64 ch]
      int r = idx - 110592;
      int t = r >> 6, ch = r & 63;
      WT3[r] = bf16s(cW3[((size_t)(t >> 1) * 64 + ch) * 2 + (t & 1)]);
    } else if (idx < 111808) {           // combined biases [3][64]
      int r = idx - 111616;
      int layer = r >> 6, ch = r & 63;
      float v;
      if (layer == 0) v = (ch < 32) ? fb0[ch] : cb0[ch - 32];
      else if (layer == 1) v = cb1[ch] + fb1[ch];
      else v = cb2[ch] + fb2[ch];
      BIA[r] = v;
    }
  } else {
    // Xb [n,64] bf16, 8 ch/thread (16B): g==0 -> x0..x3,0,0,0,0; else zeros
    int idx = ((int)blockIdx.x - fillBlocks - prepBlocks) * blockDim.x + threadIdx.x;
    if (idx >= n * 8) return;
    int i = idx >> 3, g = idx & 7;
    uint4 val = make_uint4(0u, 0u, 0u, 0u);
    if (g == 0) {
      float4 x = *(const float4*)(X + (size_t)i * 4);
      val.x = pack2(x.x, x.y);
      val.y = pack2(x.z, x.w);
    }
    *(uint4*)(Xb + (size_t)i * 64 + g * 8) = val;
  }
}

// ---------- unified conv layer: pipelined uniform gather + SALU switch + GEMM ----------
// flags: bit0 = add resid (fp32), bit1 = write fp32 out, bit2 = T pass
__global__ __launch_bounds__(1024, 8) void conv_agg(
    const unsigned short* __restrict__ prev,     // [n,64] bf16 (128B rows)
    const int* __restrict__ cnt, const int* __restrict__ jw,
    const short* __restrict__ WTn,               // [64,576] bf16
    const float* __restrict__ bias,              // [64] combined
    const float* __restrict__ resid,             // fp32 (flags&1)
    float* __restrict__ outF32,                  // fp32 (flags&2)
    unsigned short* __restrict__ outAnsc,        // [n,64] bf16
    const short* __restrict__ WT3,               // [16,64] bf16 (flags&4)
    float* __restrict__ T, int flags, int n) {   // [n,18] fp32 (flags&4)
  __shared__ __align__(16) unsigned short sA[16 * 584];
  __shared__ __align__(16) unsigned short sC[16 * 72];
  const int tid = threadIdx.x;
  const int w = tid >> 6;
  const int lane = tid & 63;
  const unsigned ln2 = (unsigned)lane * 2u;  // u16 per lane = channel
  const int nodeBase = blockIdx.x * 16;
  const int i = nodeBase + w;
  const bool valid = (i < n);
  const int ic = valid ? i : 0;
  const int* jrow = (const int*)rfl64((unsigned long long)(jw + (size_t)ic * CAP));
  const int* cptr = (const int*)rfl64((unsigned long long)(cnt + ic));
  LOAD_RECS32Q(jrow, cptr, mraw);
  const int m = valid ? min(mraw, CAP) : 0;
  const unsigned short own = prev[(size_t)ic * 64 + lane];
  float aS0 = 0, aS1 = 0, aS2 = 0, aS3 = 0, aS4 = 0, aS5 = 0, aS6 = 0, aS7 = 0;
  unsigned u0, u1, u2, u3, u4, u5, u6, u7;
  unsigned u8, u9, u10, u11, u12, u13, u14, u15;
#define GSETU(G, V) { int v_ = (V);                                         \
    u##G = ((((unsigned)v_) >> 10) & 0xFFFFFF80u) + ln2; }
#define GISSUE16_W8(BASE)                                                   \
  asm volatile("global_load_ushort %0, %0, %[bb]\n\t"                       \
               "global_load_ushort %1, %1, %[bb]\n\t"                       \
               "global_load_ushort %2, %2, %[bb]\n\t"                       \
               "global_load_ushort %3, %3, %[bb]\n\t"                       \
               "global_load_ushort %4, %4, %[bb]\n\t"                       \
               "global_load_ushort %5, %5, %[bb]\n\t"                       \
               "global_load_ushort %6, %6, %[bb]\n\t"                       \
               "global_load_ushort %7, %7, %[bb]\n\t"                       \
               "global_load_ushort %8, %8, %[bb]\n\t"                       \
               "global_load_ushort %9, %9, %[bb]\n\t"                       \
               "global_load_ushort %10, %10, %[bb]\n\t"                     \
               "global_load_ushort %11, %11, %[bb]\n\t"                     \
               "global_load_ushort %12, %12, %[bb]\n\t"                     \
               "global_load_ushort %13, %13, %[bb]\n\t"                     \
               "global_load_ushort %14, %14, %[bb]\n\t"                     \
               "global_load_ushort %15, %15, %[bb]\n\t"                     \
               "s_waitcnt vmcnt(8)"                                         \
               : "+v"(u0), "+v"(u1), "+v"(u2), "+v"(u3),                    \
                 "+v"(u4), "+v"(u5), "+v"(u6), "+v"(u7),                    \
                 "+v"(u8), "+v"(u9), "+v"(u10), "+v"(u11),                  \
                 "+v"(u12), "+v"(u13), "+v"(u14), "+v"(u15)                 \
               : [bb] "s"(BASE)                                             \
               : "memory")
#define WAITV0_HI                                                           \
  asm volatile("s_waitcnt vmcnt(0)"                                         \
               : "+v"(u8), "+v"(u9), "+v"(u10), "+v"(u11),                  \
                 "+v"(u12), "+v"(u13), "+v"(u14), "+v"(u15)                 \
               :: "memory")
#define GCONSU(G, V) { int v_ = (V);                                        \
    float w0_ = dec_w0(v_);                                                 \
    float w1_ = dec_sf(v_) - w0_;                                           \
    float xv_ = __uint_as_float(u##G << 16);                                \
    switch ((((unsigned)v_) >> 14) & 7u) {                                  \
      case 0: aS0 = fmaf(w0_, xv_, aS0); aS1 = fmaf(w1_, xv_, aS1); break;  \
      case 1: aS1 = fmaf(w0_, xv_, aS1); aS2 = fmaf(w1_, xv_, aS2); break;  \
      case 2: aS2 = fmaf(w0_, xv_, aS2); aS3 = fmaf(w1_, xv_, aS3); break;  \
      case 3: aS3 = fmaf(w0_, xv_, aS3); aS4 = fmaf(w1_, xv_, aS4); break;  \
      case 4: aS4 = fmaf(w0_, xv_, aS4); aS5 = fmaf(w1_, xv_, aS5); break;  \
      case 5: aS5 = fmaf(w0_, xv_, aS5); aS6 = fmaf(w1_, xv_, aS6); break;  \
      case 6: aS6 = fmaf(w0_, xv_, aS6); aS7 = fmaf(w1_, xv_, aS7); break;  \
      default: break;                                                       \
    } }
  // batch 1: edges 0..15 (pads -> row 0, weight 0)
  GSETU(0, RECK(0))   GSETU(1, RECK(1))   GSETU(2, RECK(2))   GSETU(3, RECK(3))
  GSETU(4, RECK(4))   GSETU(5, RECK(5))   GSETU(6, RECK(6))   GSETU(7, RECK(7))
  GSETU(8, RECK(8))   GSETU(9, RECK(9))   GSETU(10, RECK(10)) GSETU(11, RECK(11))
  GSETU(12, RECK(12)) GSETU(13, RECK(13)) GSETU(14, RECK(14)) GSETU(15, RECK(15))
  GISSUE16_W8(prev);
  GCONSU(0, RECK(0)) GCONSU(1, RECK(1)) GCONSU(2, RECK(2)) GCONSU(3, RECK(3))
  GCONSU(4, RECK(4)) GCONSU(5, RECK(5)) GCONSU(6, RECK(6)) GCONSU(7, RECK(7))
  WAITV0_HI;
  GCONSU(8, RECK(8))   GCONSU(9, RECK(9))   GCONSU(10, RECK(10))
  GCONSU(11, RECK(11)) GCONSU(12, RECK(12)) GCONSU(13, RECK(13))
  GCONSU(14, RECK(14)) GCONSU(15, RECK(15))
  if (m > 16) {                              // batch 2: edges 16..31
    GSETU(0, RECK(16))  GSETU(1, RECK(17))  GSETU(2, RECK(18))  GSETU(3, RECK(19))
    GSETU(4, RECK(20))  GSETU(5, RECK(21))  GSETU(6, RECK(22))  GSETU(7, RECK(23))
    GSETU(8, RECK(24))  GSETU(9, RECK(25))  GSETU(10, RECK(26)) GSETU(11, RECK(27))
    GSETU(12, RECK(28)) GSETU(13, RECK(29)) GSETU(14, RECK(30)) GSETU(15, RECK(31))
    GISSUE16_W8(prev);
    GCONSU(0, RECK(16)) GCONSU(1, RECK(17)) GCONSU(2, RECK(18)) GCONSU(3, RECK(19))
    GCONSU(4, RECK(20)) GCONSU(5, RECK(21)) GCONSU(6, RECK(22)) GCONSU(7, RECK(23))
    WAITV0_HI;
    GCONSU(8, RECK(24))  GCONSU(9, RECK(25))  GCONSU(10, RECK(26))
    GCONSU(11, RECK(27)) GCONSU(12, RECK(28)) GCONSU(13, RECK(29))
    GCONSU(14, RECK(30)) GCONSU(15, RECK(31))
    if (m > 32) {                            // batch 3: edges 32..47 (rare)
      LOAD_RECS16TQ(jrow);
      GSETU(0, RECT(0))   GSETU(1, RECT(1))   GSETU(2, RECT(2))   GSETU(3, RECT(3))
      GSETU(4, RECT(4))   GSETU(5, RECT(5))   GSETU(6, RECT(6))   GSETU(7, RECT(7))
      GSETU(8, RECT(8))   GSETU(9, RECT(9))   GSETU(10, RECT(10)) GSETU(11, RECT(11))
      GSETU(12, RECT(12)) GSETU(13, RECT(13)) GSETU(14, RECT(14)) GSETU(15, RECT(15))
      GISSUE16_W8(prev);
      GCONSU(0, RECT(0)) GCONSU(1, RECT(1)) GCONSU(2, RECT(2)) GCONSU(3, RECT(3))
      GCONSU(4, RECT(4)) GCONSU(5, RECT(5)) GCONSU(6, RECT(6)) GCONSU(7, RECT(7))
      WAITV0_HI;
      GCONSU(8, RECT(8))   GCONSU(9, RECT(9))   GCONSU(10, RECT(10))
      GCONSU(11, RECT(11)) GCONSU(12, RECT(12)) GCONSU(13, RECT(13))
      GCONSU(14, RECT(14)) GCONSU(15, RECT(15))
    }
  }
#undef GSETU
#undef GISSUE16_W8
#undef WAITV0_HI
#undef GCONSU
  {
    unsigned short* sAr = sA + w * 584;      // K layout: s*64+ch, own at 512+ch
    sAr[0 * 64 + lane] = (unsigned short)bf16s(aS0);
    sAr[1 * 64 + lane] = (unsigned short)bf16s(aS1);
    sAr[2 * 64 + lane] = (unsigned short)bf16s(aS2);
    sAr[3 * 64 + lane] = (unsigned short)bf16s(aS3);
    sAr[4 * 64 + lane] = (unsigned short)bf16s(aS4);
    sAr[5 * 64 + lane] = (unsigned short)bf16s(aS5);
    sAr[6 * 64 + lane] = (unsigned short)bf16s(aS6);
    sAr[7 * 64 + lane] = (unsigned short)bf16s(aS7);
    sAr[512 + lane] = own;
  }
  __syncthreads();

  if (w < 4) {                               // GEMM [16,576]@[576,64], tile t=w
    const int mrow = lane & 15, quad = lane >> 4, t = w;
    const unsigned rowoff = (unsigned)((t * 16 + mrow) * 1152 + quad * 16);
    const unsigned short* brow = sA + mrow * 584 + quad * 8;
    f32x4 acc4 = {0, 0, 0, 0};
    short8 f0, f1, f2, f3, f4, f5;
#define WLOAD6(CO)                                                          \
  asm volatile("global_load_dwordx4 %0, %[vo], %[bb] offset:0\n\t"          \
               "global_load_dwordx4 %1, %[vo], %[bb] offset:64\n\t"         \
               "global_load_dwordx4 %2, %[vo], %[bb] offset:128\n\t"        \
               "global_load_dwordx4 %3, %[vo], %[bb] offset:192\n\t"        \
               "global_load_dwordx4 %4, %[vo], %[bb] offset:256\n\t"        \
               "global_load_dwordx4 %5, %[vo], %[bb] offset:320\n\t"        \
               "s_waitcnt vmcnt(0)"                                         \
               : "=&v"(f0), "=&v"(f1), "=&v"(f2), "=&v"(f3),                \
                 "=&v"(f4), "=&v"(f5)                                       \
               : [vo] "v"(rowoff + (CO)), [bb] "s"(WTn)                     \
               : "memory")
#define MM6(KK0)                                                            \
  acc4 = __builtin_amdgcn_mfma_f32_16x16x32_bf16(                           \
      f0, *(const short8*)(brow + ((KK0) + 0) * 32), acc4, 0, 0, 0);        \
  acc4 = __builtin_amdgcn_mfma_f32_16x16x32_bf16(                           \
      f1, *(const short8*)(brow + ((KK0) + 1) * 32), acc4, 0, 0, 0);        \
  acc4 = __builtin_amdgcn_mfma_f32_16x16x32_bf16(                           \
      f2, *(const short8*)(brow + ((KK0) + 2) * 32), acc4, 0, 0, 0);        \
  acc4 = __builtin_amdgcn_mfma_f32_16x16x32_bf16(                           \
      f3, *(const short8*)(brow + ((KK0) + 3) * 32), acc4, 0, 0, 0);        \
  acc4 = __builtin_amdgcn_mfma_f32_16x16x32_bf16(                           \
      f4, *(const short8*)(brow + ((KK0) + 4) * 32), acc4, 0, 0, 0);        \
  acc4 = __builtin_amdgcn_mfma_f32_16x16x32_bf16(                           \
      f5, *(const short8*)(brow + ((KK0) + 5) * 32), acc4, 0, 0, 0);
    WLOAD6(0);    MM6(0);
    WLOAD6(384);  MM6(6);
    WLOAD6(768);  MM6(12);
#undef WLOAD6
#undef MM6
    const int node2 = nodeBase + mrow;
    const int ch0 = t * 16 + quad * 4;
    if (node2 < n) {
      float4 bb4 = *(const float4*)(bias + ch0);
      float4 rv = make_float4(0.f, 0.f, 0.f, 0.f);
      if (flags & 1) rv = *(const float4*)(resid + (size_t)node2 * 64 + ch0);
      float o0 = acc4[0] + bb4.x + rv.x;
      float o1 = acc4[1] + bb4.y + rv.y;
      float o2 = acc4[2] + bb4.z + rv.z;
      float o3 = acc4[3] + bb4.w + rv.w;
      if (flags & 2) {
        *(float2*)(outF32 + (size_t)node2 * 64 + ch0) = make_float2(o0, o1);
        *(float2*)(outF32 + (size_t)node2 * 64 + ch0 + 2) = make_float2(o2, o3);
      }
      unsigned lo = pack2(fmaxf(o0, 0.f), fmaxf(o1, 0.f));
      unsigned hi = pack2(fmaxf(o2, 0.f), fmaxf(o3, 0.f));
      *(uint2*)(outAnsc + (size_t)node2 * 64 + ch0) = make_uint2(lo, hi);
      if (flags & 4) {
        *(unsigned*)(sC + mrow * 72 + ch0) = lo;
        *(unsigned*)(sC + mrow * 72 + ch0 + 2) = hi;
      }
    } else if (flags & 4) {
      *(unsigned*)(sC + mrow * 72 + ch0) = 0u;
      *(unsigned*)(sC + mrow * 72 + ch0 + 2) = 0u;
    }
  }
  if (flags & 4) {                           // T = ansc2 @ cW3 tail
    __syncthreads();
    if (w == 0) {
      const int mrow = lane & 15, quad = lane >> 4;
      short8 b0 = *(const short8*)(sC + mrow * 72 + quad * 8);
      short8 b1 = *(const short8*)(sC + mrow * 72 + quad * 8 + 32);
      short8 a0v = *(const short8*)(WT3 + mrow * 64 + quad * 8);
      short8 a1v = *(const short8*)(WT3 + mrow * 64 + quad * 8 + 32);
      f32x4 acc4 = {0, 0, 0, 0};
      acc4 = __builtin_amdgcn_mfma_f32_16x16x32_bf16(a0v, b0, acc4, 0, 0, 0);
      acc4 = __builtin_amdgcn_mfma_f32_16x16x32_bf16(a1v, b1, acc4, 0, 0, 0);
      const int node2 = nodeBase + mrow;
      if (node2 < n) {
        float* tr = T + (size_t)node2 * 18 + quad * 4;
        *(float2*)(tr) = make_float2(acc4[0], acc4[1]);
        *(float2*)(tr + 2) = make_float2(acc4[2], acc4[3]);
      }
    }
  }
}

// ---------- layer 3: wave per node, lane = edge; 16B/edge from T; + lin ----------
__global__ __launch_bounds__(256, 4) void layer3_kernel(
    const unsigned short* __restrict__ Xb,  // ansc2 [n,64] bf16
    const float* __restrict__ T,            // [n,18] fp32 (L2-resident)
    const int* __restrict__ cnt, const int* __restrict__ jw,
    const float* __restrict__ cb3, const float* __restrict__ fb3,
    const float* __restrict__ fW3,          // [64,2]
    float* __restrict__ out, int n) {
  const int lane = threadIdx.x & 63;
  const int i = (blockIdx.x * blockDim.x + threadIdx.x) >> 6;
  if (i >= n) return;
  const int m = min(cnt[i], CAP);
  float c0 = 0.0f, c1 = 0.0f;
  if (lane < m) {                      // lane = edge index (real records only)
    int v = jw[(size_t)i * CAP + lane];
    unsigned j = (unsigned)v >> 17;
    unsigned p = ((unsigned)v >> 14) & 7u;
    unsigned off9 = j * 9u + p;        // T row = 18 floats = 9 x 8B slots
    float w0 = dec_w0(v);
    float w1 = 1.0f - w0;
    const float* tb = T + (size_t)off9 * 2;
    float2 ta = *(const float2*)(tb);
    float2 tc = *(const float2*)(tb + 2);
    c0 = w0 * ta.x + w1 * tc.x;
    c1 = w0 * ta.y + w1 * tc.y;
  }
  float xi = b2f(Xb[(size_t)i * 64 + lane]);
  float2 fw = *(const float2*)(fW3 + lane * 2);
  c0 = fmaf(xi, fw.x, c0);
  c1 = fmaf(xi, fw.y, c1);
  #pragma unroll
  for (int off = 32; off > 0; off >>= 1) {
    c0 += __shfl_xor(c0, off, 64);
    c1 += __shfl_xor(c1, off, 64);
  }
  if (lane == 0) {
    out[(size_t)i * 2 + 0] = c0 + cb3[0] + fb3[0];
    out[(size_t)i * 2 + 1] = c1 + cb3[1] + fb3[1];
  }
}

extern "C" void kernel_launch(void* const* d_in, const int* in_sizes, int n_in,
                              void* d_out, int out_size, void* d_ws, size_t ws_size,
                              hipStream_t stream) {
  const float* X    = (const float*)d_in[0];
  const int*   fi   = (const int*)d_in[1];
  const int*   fj   = (const int*)d_in[2];
  const float* dist = (const float*)d_in[3];
  const float* cW0 = (const float*)d_in[4];  const float* cb0 = (const float*)d_in[5];
  const float* fW0 = (const float*)d_in[6];  const float* fb0 = (const float*)d_in[7];
  const float* cW1 = (const float*)d_in[8];  const float* cb1 = (const float*)d_in[9];
  const float* fW1 = (const float*)d_in[10]; const float* fb1 = (const float*)d_in[11];
  const float* cW2 = (const float*)d_in[12]; const float* cb2 = (const float*)d_in[13];
  const float* fW2 = (const float*)d_in[14]; const float* fb2 = (const float*)d_in[15];
  const float* cW3 = (const float*)d_in[16]; const float* cb3 = (const float*)d_in[17];
  const float* fW3 = (const float*)d_in[18]; const float* fb3 = (const float*)d_in[19];
  float* out = (float*)d_out;

  const int n  = in_sizes[0] / 4;  // N = 30000
  const int nE = in_sizes[1];      // E = 480000

  // workspace (~31 MB):
  // ansc0 bf16[n*64] | ans1 f32[n*64] | ansc1 bf16[n*64] | ansc2 bf16[n*64]
  // | T f32[n*18] | Xb u16[n*64] | W1T | W2T | W0T | WT3 | BIA | jw | cnt
  unsigned short* ansc0 = (unsigned short*)d_ws;
  float*          ans1  = (float*)(ansc0 + (size_t)n * 64);
  unsigned short* ansc1 = (unsigned short*)(ans1 + (size_t)n * 64);
  unsigned short* ansc2 = ansc1 + (size_t)n * 64;
  float*          T     = (float*)(ansc2 + (size_t)n * 64);
  unsigned short* Xb16  = (unsigned short*)(T + (size_t)n * 18);
  short* W1T = (short*)(Xb16 + (size_t)n * 64);
  short* W2T = W1T + 36864;
  short* W0T = W2T + 36864;
  short* WT3 = W0T + 36864;
  float* BIA = (float*)(WT3 + 1024);
  int*   jw  = (int*)(BIA + 192);
  int*   cnt = jw + (size_t)n * CAP;

  hipMemsetAsync(jw, 0, ((size_t)n * CAP + n) * sizeof(int), stream);
  const int fillBlocks = (nE + 255) / 256;
  const int prepBlocks = (111808 + 255) / 256;
  const int xbBlocks   = (n * 8 + 255) / 256;
  fill_prep<<<fillBlocks + prepBlocks + xbBlocks, 256, 0, stream>>>(
      dist, fi, fj, cnt, jw, nE,
      cW0, fW0, cb0, fb0, cW1, fW1, cb1, fb1, cW2, fW2, cb2, fb2, cW3,
      W0T, W1T, W2T, WT3, BIA, X, Xb16, n, fillBlocks, prepBlocks);

  const int nodeBlocks = (n + 15) / 16;
  // layer0: conv_agg on padded Xb with W0T (flags=0)
  conv_agg<<<nodeBlocks, 1024, 0, stream>>>(Xb16, cnt, jw, W0T, BIA,
                                            ans1, ans1, ansc0, WT3, T, 0, n);
  // conv1: ansc0 -> ans1 (fp32) + ansc1 (flags=2)
  conv_agg<<<nodeBlocks, 1024, 0, stream>>>(ansc0, cnt, jw, W1T, BIA + 64,
                                            ans1, ans1, ansc1, WT3, T, 2, n);
  // conv2: ansc1 (+ans1 resid) -> ansc2 + T (flags=5)
  conv_agg<<<nodeBlocks, 1024, 0, stream>>>(ansc1, cnt, jw, W2T, BIA + 128,
                                            ans1, ans1, ansc2, WT3, T, 5, n);
  // layer3
  layer3_kernel<<<(n * 64 + 255) / 256, 256, 0, stream>>>(ansc2, T, cnt, jw,
                                                          cb3, fb3, fW3, out, n);
}

// Round 10
// 245.465 us; speedup vs baseline: 1.0955x; 1.0161x over previous
//
#include <hip/hip_runtime.h>

// RbfNet on MI355X — round 30: SORTED-BY-P + ROLLING-PAIR CONSUME.
// R28/R29 ran at the same ~45us despite halving VALU -> per-edge instruction
// count is the limiter (if-converted 8-slot select ~26 VALU-cy + ~40 SALU per
// slot, 28 slots/wave incl pads; model now closes with measured 108K cy).
// Fix: sort each node's edges by p -> the select disappears:
// - rolling accumulators curA (slot p), curB (slot p+1); on p-transition
//   (uniform cmp, ~6/node) flush to LDS sA via ds_write (each slot written
//   once; sA pre-zeroed). Per edge: 2 fmac + decode + 1 cmp ~= 10 inst.
// - compact list = exact m (no pad consumption; 28 -> 16 slots avg).
// - fill bins edges into 8 per-(i,p) buckets (cap 16, P(ovfl)~1e-10);
//   new compact_kernel (wave/node) emits sorted-compact jw + cnt.
// - loads: R29's proven named-scalar asm batches, pads clamped to row 0.
// Record (4B): j(15b)<<17 | p(3b)<<14 | wq(14b); w0 = as_float(0x3F800000
// | wq<<9) - 1.0; w1 = 2.0 - f. Byte offset = (rec>>10) & ~0x7F (= j*128).

#define CAP 48

typedef __attribute__((ext_vector_type(8))) short short8;
typedef __attribute__((ext_vector_type(4))) float f32x4;
typedef int v4i __attribute__((ext_vector_type(4)));

__device__ __forceinline__ short bf16s(float f) {   // fp32 -> bf16 RNE
  unsigned u = __float_as_uint(f);
  return (short)((u + 0x7FFF + ((u >> 16) & 1)) >> 16);
}
__device__ __forceinline__ float b2f(unsigned short s) {
  return __uint_as_float(((unsigned)s) << 16);
}
__device__ __forceinline__ unsigned pack2(float a, float b) {
  return (unsigned)(unsigned short)bf16s(a) | ((unsigned)(unsigned short)bf16s(b) << 16);
}
__device__ __forceinline__ float dec14(int v) {     // w0 = wq14 * 2^-14
  return __uint_as_float(0x3F800000u | (((unsigned)v & 0x3FFFu) << 9)) - 1.0f;
}
__device__ __forceinline__ unsigned long long rfl64(unsigned long long x) {
  unsigned lo = __builtin_amdgcn_readfirstlane((unsigned)x);
  unsigned hi = __builtin_amdgcn_readfirstlane((unsigned)(x >> 32));
  return ((unsigned long long)hi << 32) | (unsigned long long)lo;
}

// ---- record fetch into SGPRs (proven R26-R29 pattern) ----
#define LOAD_RECS32Q(JROW, CPTR, MRAW)                                      \
  v4i q0, q1, q2, q3, q4, q5, q6, q7;                                       \
  int MRAW;                                                                 \
  asm volatile("s_load_dwordx4 %0, %9, 0x0\n\t"                             \
               "s_load_dwordx4 %1, %9, 0x10\n\t"                            \
               "s_load_dwordx4 %2, %9, 0x20\n\t"                            \
               "s_load_dwordx4 %3, %9, 0x30\n\t"                            \
               "s_load_dwordx4 %4, %9, 0x40\n\t"                            \
               "s_load_dwordx4 %5, %9, 0x50\n\t"                            \
               "s_load_dwordx4 %6, %9, 0x60\n\t"                            \
               "s_load_dwordx4 %7, %9, 0x70\n\t"                            \
               "s_load_dword %8, %10, 0x0\n\t"                              \
               "s_waitcnt lgkmcnt(0)"                                       \
               : "=&s"(q0), "=&s"(q1), "=&s"(q2), "=&s"(q3), "=&s"(q4),     \
                 "=&s"(q5), "=&s"(q6), "=&s"(q7), "=&s"(MRAW)               \
               : "s"(JROW), "s"(CPTR)                                       \
               : "memory")

#define LOAD_RECS16TQ(JROW)                                                 \
  v4i qt0, qt1, qt2, qt3;                                                   \
  asm volatile("s_load_dwordx4 %0, %4, 0x80\n\t"                            \
               "s_load_dwordx4 %1, %4, 0x90\n\t"                            \
               "s_load_dwordx4 %2, %4, 0xA0\n\t"                            \
               "s_load_dwordx4 %3, %4, 0xB0\n\t"                            \
               "s_waitcnt lgkmcnt(0)"                                       \
               : "=&s"(qt0), "=&s"(qt1), "=&s"(qt2), "=&s"(qt3)             \
               : "s"(JROW)                                                  \
               : "memory")

#define RECK(K) ((K) < 4 ? q0[(K) & 3] : (K) < 8 ? q1[(K) & 3] :            \
                 (K) < 12 ? q2[(K) & 3] : (K) < 16 ? q3[(K) & 3] :          \
                 (K) < 20 ? q4[(K) & 3] : (K) < 24 ? q5[(K) & 3] :          \
                 (K) < 28 ? q6[(K) & 3] : q7[(K) & 3])
#define RECT(K) ((K) < 4 ? qt0[(K) & 3] : (K) < 8 ? qt1[(K) & 3] :          \
                 (K) < 12 ? qt2[(K) & 3] : qt3[(K) & 3])

// ---------- fused: edge-bucket bin | weight/bias prep | Xb prep ----------
__global__ void fill_prep(const float* __restrict__ dist,
                          const int* __restrict__ fi, const int* __restrict__ fj,
                          int* __restrict__ cnt8, int* __restrict__ jwB, int nE,
                          const float* __restrict__ cW0, const float* __restrict__ fW0,
                          const float* __restrict__ cb0, const float* __restrict__ fb0,
                          const float* __restrict__ cW1, const float* __restrict__ fW1,
                          const float* __restrict__ cb1, const float* __restrict__ fb1,
                          const float* __restrict__ cW2, const float* __restrict__ fW2,
                          const float* __restrict__ cb2, const float* __restrict__ fb2,
                          const float* __restrict__ cW3,
                          short* __restrict__ W0T, short* __restrict__ W1T,
                          short* __restrict__ W2T, short* __restrict__ WT3,
                          float* __restrict__ BIA,   // [3*64] combined biases
                          const float* __restrict__ X,
                          unsigned short* __restrict__ Xb, int n,
                          int fillBlocks, int prepBlocks) {
  if ((int)blockIdx.x < fillBlocks) {
    int e = blockIdx.x * blockDim.x + threadIdx.x;
    if (e >= nE) return;
    int i = fi[e], j = fj[e];
    if (i == j) return;                  // centerIgnore
    float d = fminf(1.0f, fmaxf(-1.0f, dist[e]));
    float u = (d + 1.0f) * 3.5f;         // hat centers: spacing 2/7
    int p = min((int)u, 6);
    float w0 = 1.0f - (u - (float)p);
    int wq = min((int)(w0 * 16384.0f + 0.5f), 16383);
    int pos = atomicAdd(&cnt8[i * 8 + p], 1);
    if (pos < 16)
      jwB[(size_t)i * 128 + p * 16 + pos] =
          (int)(((unsigned)j << 17) | ((unsigned)p << 14) | (unsigned)wq);
  } else if ((int)blockIdx.x < fillBlocks + prepBlocks) {
    int idx = ((int)blockIdx.x - fillBlocks) * blockDim.x + threadIdx.x;
    if (idx < 36864) {                   // W1T [64 out][576 k]
      int o = idx / 576, k = idx - o * 576;
      float v = (k < 512) ? cW1[((size_t)(k >> 6) * 64 + (k & 63)) * 64 + o]
                          : fW1[(size_t)(k - 512) * 64 + o];
      W1T[idx] = bf16s(v);
    } else if (idx < 73728) {            // W2T
      int r = idx - 36864;
      int o = r / 576, k = r - o * 576;
      float v = (k < 512) ? cW2[((size_t)(k >> 6) * 64 + (k & 63)) * 64 + o]
                          : fW2[(size_t)(k - 512) * 64 + o];
      W2T[r] = bf16s(v);
    } else if (idx < 110592) {           // W0T [64 out][576 k], mostly zero
      int r = idx - 73728;
      int o = r / 576, k = r - o * 576;
      float v = 0.0f;
      if (k < 512) {
        int s = k >> 6, ci = k & 63;
        if (ci < 4 && o >= 32) v = cW0[((size_t)s * 4 + ci) * 32 + (o - 32)];
      } else {
        int c = k - 512;
        if (c < 4 && o < 32) v = fW0[(size_t)c * 32 + o];
      }
      W0T[r] = bf16s(v);
    } else if (idx < 111616) {           // WT3 [16 t][64 ch]
      int r = idx - 110592;
      int t = r >> 6, ch = r & 63;
      WT3[r] = bf16s(cW3[((size_t)(t >> 1) * 64 + ch) * 2 + (t & 1)]);
    } else if (idx < 111808) {           // combined biases [3][64]
      int r = idx - 111616;
      int layer = r >> 6, ch = r & 63;
      float v;
      if (layer == 0) v = (ch < 32) ? fb0[ch] : cb0[ch - 32];
      else if (layer == 1) v = cb1[ch] + fb1[ch];
      else v = cb2[ch] + fb2[ch];
      BIA[r] = v;
    }
  } else {
    // Xb [n,64] bf16, 8 ch/thread (16B): g==0 -> x0..x3,0,0,0,0; else zeros
    int idx = ((int)blockIdx.x - fillBlocks - prepBlocks) * blockDim.x + threadIdx.x;
    if (idx >= n * 8) return;
    int i = idx >> 3, g = idx & 7;
    uint4 val = make_uint4(0u, 0u, 0u, 0u);
    if (g == 0) {
      float4 x = *(const float4*)(X + (size_t)i * 4);
      val.x = pack2(x.x, x.y);
      val.y = pack2(x.z, x.w);
    }
    *(uint4*)(Xb + (size_t)i * 64 + g * 8) = val;
  }
}

// ---------- compact: buckets -> sorted-compact jw + exact cnt ----------
__global__ __launch_bounds__(256, 8) void compact_kernel(
    const int* __restrict__ jwB, const int* __restrict__ cnt8,
    int* __restrict__ jw, int* __restrict__ cnt, int n) {
  const int w = threadIdx.x >> 6, lane = threadIdx.x & 63;
  const int i = blockIdx.x * 4 + w;
  if (i >= n) return;
  const int4* c8 = (const int4*)(cnt8 + (size_t)i * 8);
  int4 ca = c8[0], cb = c8[1];
  int c0 = min(ca.x, 16), c1 = min(ca.y, 16), c2 = min(ca.z, 16), c3 = min(ca.w, 16);
  int c4 = min(cb.x, 16), c5 = min(cb.y, 16), c6 = min(cb.z, 16), c7 = min(cb.w, 16);
  int tot = c0 + c1 + c2 + c3 + c4 + c5 + c6 + c7;
  if (lane == 0) cnt[i] = min(tot, CAP);
  #pragma unroll
  for (int h = 0; h < 2; ++h) {
    int s = lane + h * 64;
    int p = s >> 4, k = s & 15;
    int cp = p == 0 ? c0 : p == 1 ? c1 : p == 2 ? c2 : p == 3 ? c3
           : p == 4 ? c4 : p == 5 ? c5 : p == 6 ? c6 : c7;
    int ps = (p > 0 ? c0 : 0) + (p > 1 ? c1 : 0) + (p > 2 ? c2 : 0) +
             (p > 3 ? c3 : 0) + (p > 4 ? c4 : 0) + (p > 5 ? c5 : 0) +
             (p > 6 ? c6 : 0);
    if (k < cp) {
      int pos = ps + k;
      if (pos < CAP) jw[(size_t)i * CAP + pos] = jwB[(size_t)i * 128 + s];
    }
  }
}

// ---------- unified conv layer: batched loads + rolling-pair consume + GEMM ----------
// flags: bit0 = add resid (fp32), bit1 = write fp32 out, bit2 = T pass
__global__ __launch_bounds__(1024, 8) void conv_agg(
    const unsigned short* __restrict__ prev,     // [n,64] bf16 (128B rows)
    const int* __restrict__ cnt, const int* __restrict__ jw,
    const short* __restrict__ WTn,               // [64,576] bf16
    const float* __restrict__ bias,              // [64] combined
    const float* __restrict__ resid,             // fp32 (flags&1)
    float* __restrict__ outF32,                  // fp32 (flags&2)
    unsigned short* __restrict__ outAnsc,        // [n,64] bf16
    const short* __restrict__ WT3,               // [16,64] bf16 (flags&4)
    float* __restrict__ T, int flags, int n) {   // [n,18] fp32 (flags&4)
  __shared__ __align__(16) unsigned short sA[16 * 584];
  __shared__ __align__(16) unsigned short sC[16 * 72];
  const int tid = threadIdx.x;
  const int w = tid >> 6;
  const int lane = tid & 63;
  const unsigned ln2 = (unsigned)lane * 2u;  // u16 per lane = channel
  const int nodeBase = blockIdx.x * 16;
  const int i = nodeBase + w;
  const bool valid = (i < n);
  const int ic = valid ? i : 0;
  const int* jrow = (const int*)rfl64((unsigned long long)(jw + (size_t)ic * CAP));
  const int* cptr = (const int*)rfl64((unsigned long long)(cnt + ic));
  LOAD_RECS32Q(jrow, cptr, mraw);
  const int mloc = valid ? min(mraw, CAP) : 0;
  const unsigned short own = prev[(size_t)ic * 64 + lane];
  unsigned short* sAr = sA + w * 584;        // K layout: s*64+ch, own at 512+ch
  #pragma unroll
  for (int r = 0; r < 8; ++r) sAr[r * 64 + lane] = 0;  // zero slot rows
  sAr[512 + lane] = own;
  unsigned u0, u1, u2, u3, u4, u5, u6, u7;
  unsigned u8, u9, u10, u11, u12, u13, u14, u15;
#define GSETU(G, KCMP, RV)                                                  \
  { unsigned o_ = ((KCMP) < mloc)                                           \
        ? ((((unsigned)(RV)) >> 10) & 0xFFFFFF80u) : 0u;                    \
    u##G = o_ + ln2; }
#define GISSUE16_W8(BASE)                                                   \
  asm volatile("global_load_ushort %0, %0, %[bb]\n\t"                       \
               "global_load_ushort %1, %1, %[bb]\n\t"                       \
               "global_load_ushort %2, %2, %[bb]\n\t"                       \
               "global_load_ushort %3, %3, %[bb]\n\t"                       \
               "global_load_ushort %4, %4, %[bb]\n\t"                       \
               "global_load_ushort %5, %5, %[bb]\n\t"                       \
               "global_load_ushort %6, %6, %[bb]\n\t"                       \
               "global_load_ushort %7, %7, %[bb]\n\t"                       \
               "global_load_ushort %8, %8, %[bb]\n\t"                       \
               "global_load_ushort %9, %9, %[bb]\n\t"                       \
               "global_load_ushort %10, %10, %[bb]\n\t"                     \
               "global_load_ushort %11, %11, %[bb]\n\t"                     \
               "global_load_ushort %12, %12, %[bb]\n\t"                     \
               "global_load_ushort %13, %13, %[bb]\n\t"                     \
               "global_load_ushort %14, %14, %[bb]\n\t"                     \
               "global_load_ushort %15, %15, %[bb]\n\t"                     \
               "s_waitcnt vmcnt(8)"                                         \
               : "+v"(u0), "+v"(u1), "+v"(u2), "+v"(u3),                    \
                 "+v"(u4), "+v"(u5), "+v"(u6), "+v"(u7),                    \
                 "+v"(u8), "+v"(u9), "+v"(u10), "+v"(u11),                  \
                 "+v"(u12), "+v"(u13), "+v"(u14), "+v"(u15)                 \
               : [bb] "s"(BASE)                                             \
               : "memory")
#define WAITV0_HI                                                           \
  asm volatile("s_waitcnt vmcnt(0)"                                         \
               : "+v"(u8), "+v"(u9), "+v"(u10), "+v"(u11),                  \
                 "+v"(u12), "+v"(u13), "+v"(u14), "+v"(u15)                 \
               :: "memory")
  // rolling-pair consume: curA = slot pcur, curB = slot pcur+1 (sorted by p)
#define CONSK(KCMP, G, RV)                                                  \
  if ((KCMP) == mloc) goto cons_done;                                       \
  { int v_ = (RV);                                                          \
    int pk_ = (v_ >> 14) & 7;                                               \
    if (pk_ != pcur) {                                                      \
      sAr[pcur * 64 + lane] = (unsigned short)bf16s(curA);                  \
      if (pk_ == pcur + 1) { curA = curB; }                                 \
      else { sAr[(pcur + 1) * 64 + lane] = (unsigned short)bf16s(curB);     \
             curA = 0.0f; }                                                 \
      curB = 0.0f; pcur = pk_;                                              \
    }                                                                       \
    float f_ = __uint_as_float(0x3F800000u | (((unsigned)v_ & 0x3FFFu) << 9)); \
    float xv_ = __uint_as_float(u##G << 16);                                \
    curA = fmaf(f_ - 1.0f, xv_, curA);                                      \
    curB = fmaf(2.0f - f_, xv_, curB);                                      \
  }
  if (mloc > 0) {
    int pcur = (RECK(0) >> 14) & 7;
    float curA = 0.0f, curB = 0.0f;
    GSETU(0, 0, RECK(0))    GSETU(1, 1, RECK(1))    GSETU(2, 2, RECK(2))
    GSETU(3, 3, RECK(3))    GSETU(4, 4, RECK(4))    GSETU(5, 5, RECK(5))
    GSETU(6, 6, RECK(6))    GSETU(7, 7, RECK(7))    GSETU(8, 8, RECK(8))
    GSETU(9, 9, RECK(9))    GSETU(10, 10, RECK(10)) GSETU(11, 11, RECK(11))
    GSETU(12, 12, RECK(12)) GSETU(13, 13, RECK(13)) GSETU(14, 14, RECK(14))
    GSETU(15, 15, RECK(15))
    GISSUE16_W8(prev);
    CONSK(0, 0, RECK(0))   CONSK(1, 1, RECK(1))   CONSK(2, 2, RECK(2))
    CONSK(3, 3, RECK(3))   CONSK(4, 4, RECK(4))   CONSK(5, 5, RECK(5))
    CONSK(6, 6, RECK(6))   CONSK(7, 7, RECK(7))
    WAITV0_HI;
    CONSK(8, 8, RECK(8))   CONSK(9, 9, RECK(9))   CONSK(10, 10, RECK(10))
    CONSK(11, 11, RECK(11)) CONSK(12, 12, RECK(12)) CONSK(13, 13, RECK(13))
    CONSK(14, 14, RECK(14)) CONSK(15, 15, RECK(15))
    if (mloc > 16) {
      GSETU(0, 16, RECK(16))  GSETU(1, 17, RECK(17))  GSETU(2, 18, RECK(18))
      GSETU(3, 19, RECK(19))  GSETU(4, 20, RECK(20))  GSETU(5, 21, RECK(21))
      GSETU(6, 22, RECK(22))  GSETU(7, 23, RECK(23))  GSETU(8, 24, RECK(24))
      GSETU(9, 25, RECK(25))  GSETU(10, 26, RECK(26)) GSETU(11, 27, RECK(27))
      GSETU(12, 28, RECK(28)) GSETU(13, 29, RECK(29)) GSETU(14, 30, RECK(30))
      GSETU(15, 31, RECK(31))
      GISSUE16_W8(prev);
      CONSK(16, 0, RECK(16))  CONSK(17, 1, RECK(17))  CONSK(18, 2, RECK(18))
      CONSK(19, 3, RECK(19))  CONSK(20, 4, RECK(20))  CONSK(21, 5, RECK(21))
      CONSK(22, 6, RECK(22))  CONSK(23, 7, RECK(23))
      WAITV0_HI;
      CONSK(24, 8, RECK(24))  CONSK(25, 9, RECK(25))  CONSK(26, 10, RECK(26))
      CONSK(27, 11, RECK(27)) CONSK(28, 12, RECK(28)) CONSK(29, 13, RECK(29))
      CONSK(30, 14, RECK(30)) CONSK(31, 15, RECK(31))
      if (mloc > 32) {                       // rare tail (P ~ 1e-4)
        LOAD_RECS16TQ(jrow);
        GSETU(0, 32, RECT(0))   GSETU(1, 33, RECT(1))   GSETU(2, 34, RECT(2))
        GSETU(3, 35, RECT(3))   GSETU(4, 36, RECT(4))   GSETU(5, 37, RECT(5))
        GSETU(6, 38, RECT(6))   GSETU(7, 39, RECT(7))   GSETU(8, 40, RECT(8))
        GSETU(9, 41, RECT(9))   GSETU(10, 42, RECT(10)) GSETU(11, 43, RECT(11))
        GSETU(12, 44, RECT(12)) GSETU(13, 45, RECT(13)) GSETU(14, 46, RECT(14))
        GSETU(15, 47, RECT(15))
        GISSUE16_W8(prev);
        CONSK(32, 0, RECT(0))   CONSK(33, 1, RECT(1))   CONSK(34, 2, RECT(2))
        CONSK(35, 3, RECT(3))   CONSK(36, 4, RECT(4))   CONSK(37, 5, RECT(5))
        CONSK(38, 6, RECT(6))   CONSK(39, 7, RECT(7))
        WAITV0_HI;
        CONSK(40, 8, RECT(8))   CONSK(41, 9, RECT(9))   CONSK(42, 10, RECT(10))
        CONSK(43, 11, RECT(11)) CONSK(44, 12, RECT(12)) CONSK(45, 13, RECT(13))
        CONSK(46, 14, RECT(14)) CONSK(47, 15, RECT(15))
      }
    }
cons_done: ;
    sAr[pcur * 64 + lane] = (unsigned short)bf16s(curA);      // end flush
    sAr[(pcur + 1) * 64 + lane] = (unsigned short)bf16s(curB); // pcur<=6 ✓
  }
#undef GSETU
#undef GISSUE16_W8
#undef WAITV0_HI
#undef CONSK
  __syncthreads();

  if (w < 4) {                               // GEMM [16,576]@[576,64], tile t=w
    const int mrow = lane & 15, quad = lane >> 4, t = w;
    const unsigned rowoff = (unsigned)((t * 16 + mrow) * 1152 + quad * 16);
    const unsigned short* brow = sA + mrow * 584 + quad * 8;
    f32x4 acc4 = {0, 0, 0, 0};
    short8 f0, f1, f2, f3, f4, f5;
#define WLOAD6(CO)                                                          \
  asm volatile("global_load_dwordx4 %0, %[vo], %[bb] offset:0\n\t"          \
               "global_load_dwordx4 %1, %[vo], %[bb] offset:64\n\t"         \
               "global_load_dwordx4 %2, %[vo], %[bb] offset:128\n\t"        \
               "global_load_dwordx4 %3, %[vo], %[bb] offset:192\n\t"        \
               "global_load_dwordx4 %4, %[vo], %[bb] offset:256\n\t"        \
               "global_load_dwordx4 %5, %[vo], %[bb] offset:320\n\t"        \
               "s_waitcnt vmcnt(0)"                                         \
               : "=&v"(f0), "=&v"(f1), "=&v"(f2), "=&v"(f3),                \
                 "=&v"(f4), "=&v"(f5)                                       \
               : [vo] "v"(rowoff + (CO)), [bb] "s"(WTn)                     \
               : "memory")
#define MM6(KK0)                                                            \
  acc4 = __builtin_amdgcn_mfma_f32_16x16x32_bf16(                           \
      f0, *(const short8*)(brow + ((KK0) + 0) * 32), acc4, 0, 0, 0);        \
  acc4 = __builtin_amdgcn_mfma_f32_16x16x32_bf16(                           \
      f1, *(const short8*)(brow + ((KK0) + 1) * 32), acc4, 0, 0, 0);        \
  acc4 = __builtin_amdgcn_mfma_f32_16x16x32_bf16(                           \
      f2, *(const short8*)(brow + ((KK0) + 2) * 32), acc4, 0, 0, 0);        \
  acc4 = __builtin_amdgcn_mfma_f32_16x16x32_bf16(                           \
      f3, *(const short8*)(brow + ((KK0) + 3) * 32), acc4, 0, 0, 0);        \
  acc4 = __builtin_amdgcn_mfma_f32_16x16x32_bf16(                           \
      f4, *(const short8*)(brow + ((KK0) + 4) * 32), acc4, 0, 0, 0);        \
  acc4 = __builtin_amdgcn_mfma_f32_16x16x32_bf16(                           \
      f5, *(const short8*)(brow + ((KK0) + 5) * 32), acc4, 0, 0, 0);
    WLOAD6(0);    MM6(0);
    WLOAD6(384);  MM6(6);
    WLOAD6(768);  MM6(12);
#undef WLOAD6
#undef MM6
    const int node2 = nodeBase + mrow;
    const int ch0 = t * 16 + quad * 4;
    if (node2 < n) {
      float4 bb4 = *(const float4*)(bias + ch0);
      float4 rv = make_float4(0.f, 0.f, 0.f, 0.f);
      if (flags & 1) rv = *(const float4*)(resid + (size_t)node2 * 64 + ch0);
      float o0 = acc4[0] + bb4.x + rv.x;
      float o1 = acc4[1] + bb4.y + rv.y;
      float o2 = acc4[2] + bb4.z + rv.z;
      float o3 = acc4[3] + bb4.w + rv.w;
      if (flags & 2) {
        *(float2*)(outF32 + (size_t)node2 * 64 + ch0) = make_float2(o0, o1);
        *(float2*)(outF32 + (size_t)node2 * 64 + ch0 + 2) = make_float2(o2, o3);
      }
      unsigned lo = pack2(fmaxf(o0, 0.f), fmaxf(o1, 0.f));
      unsigned hi = pack2(fmaxf(o2, 0.f), fmaxf(o3, 0.f));
      *(uint2*)(outAnsc + (size_t)node2 * 64 + ch0) = make_uint2(lo, hi);
      if (flags & 4) {
        *(unsigned*)(sC + mrow * 72 + ch0) = lo;
        *(unsigned*)(sC + mrow * 72 + ch0 + 2) = hi;
      }
    } else if (flags & 4) {
      *(unsigned*)(sC + mrow * 72 + ch0) = 0u;
      *(unsigned*)(sC + mrow * 72 + ch0 + 2) = 0u;
    }
  }
  if (flags & 4) {                           // T = ansc2 @ cW3 tail
    __syncthreads();
    if (w == 0) {
      const int mrow = lane & 15, quad = lane >> 4;
      short8 b0 = *(const short8*)(sC + mrow * 72 + quad * 8);
      short8 b1 = *(const short8*)(sC + mrow * 72 + quad * 8 + 32);
      short8 a0v = *(const short8*)(WT3 + mrow * 64 + quad * 8);
      short8 a1v = *(const short8*)(WT3 + mrow * 64 + quad * 8 + 32);
      f32x4 acc4 = {0, 0, 0, 0};
      acc4 = __builtin_amdgcn_mfma_f32_16x16x32_bf16(a0v, b0, acc4, 0, 0, 0);
      acc4 = __builtin_amdgcn_mfma_f32_16x16x32_bf16(a1v, b1, acc4, 0, 0, 0);
      const int node2 = nodeBase + mrow;
      if (node2 < n) {
        float* tr = T + (size_t)node2 * 18 + quad * 4;
        *(float2*)(tr) = make_float2(acc4[0], acc4[1]);
        *(float2*)(tr + 2) = make_float2(acc4[2], acc4[3]);
      }
    }
  }
}

// ---------- layer 3: wave per node, lane = edge; 16B/edge from T; + lin ----------
__global__ __launch_bounds__(256, 4) void layer3_kernel(
    const unsigned short* __restrict__ Xb,  // ansc2 [n,64] bf16
    const float* __restrict__ T,            // [n,18] fp32 (L2-resident)
    const int* __restrict__ cnt, const int* __restrict__ jw,
    const float* __restrict__ cb3, const float* __restrict__ fb3,
    const float* __restrict__ fW3,          // [64,2]
    float* __restrict__ out, int n) {
  const int lane = threadIdx.x & 63;
  const int i = (blockIdx.x * blockDim.x + threadIdx.x) >> 6;
  if (i >= n) return;
  const int m = min(cnt[i], CAP);
  float c0 = 0.0f, c1 = 0.0f;
  if (lane < m) {                      // lane = edge index (exact m, no pads)
    int v = jw[(size_t)i * CAP + lane];
    unsigned j = (unsigned)v >> 17;
    unsigned p = ((unsigned)v >> 14) & 7u;
    unsigned off9 = j * 9u + p;        // T row = 18 floats = 9 x 8B slots
    float w0 = dec14(v);
    float w1 = 1.0f - w0;
    const float* tb = T + (size_t)off9 * 2;
    float2 ta = *(const float2*)(tb);
    float2 tc = *(const float2*)(tb + 2);
    c0 = w0 * ta.x + w1 * tc.x;
    c1 = w0 * ta.y + w1 * tc.y;
  }
  float xi = b2f(Xb[(size_t)i * 64 + lane]);
  float2 fw = *(const float2*)(fW3 + lane * 2);
  c0 = fmaf(xi, fw.x, c0);
  c1 = fmaf(xi, fw.y, c1);
  #pragma unroll
  for (int off = 32; off > 0; off >>= 1) {
    c0 += __shfl_xor(c0, off, 64);
    c1 += __shfl_xor(c1, off, 64);
  }
  if (lane == 0) {
    out[(size_t)i * 2 + 0] = c0 + cb3[0] + fb3[0];
    out[(size_t)i * 2 + 1] = c1 + cb3[1] + fb3[1];
  }
}

extern "C" void kernel_launch(void* const* d_in, const int* in_sizes, int n_in,
                              void* d_out, int out_size, void* d_ws, size_t ws_size,
                              hipStream_t stream) {
  const float* X    = (const float*)d_in[0];
  const int*   fi   = (const int*)d_in[1];
  const int*   fj   = (const int*)d_in[2];
  const float* dist = (const float*)d_in[3];
  const float* cW0 = (const float*)d_in[4];  const float* cb0 = (const float*)d_in[5];
  const float* fW0 = (const float*)d_in[6];  const float* fb0 = (const float*)d_in[7];
  const float* cW1 = (const float*)d_in[8];  const float* cb1 = (const float*)d_in[9];
  const float* fW1 = (const float*)d_in[10]; const float* fb1 = (const float*)d_in[11];
  const float* cW2 = (const float*)d_in[12]; const float* cb2 = (const float*)d_in[13];
  const float* fW2 = (const float*)d_in[14]; const float* fb2 = (const float*)d_in[15];
  const float* cW3 = (const float*)d_in[16]; const float* cb3 = (const float*)d_in[17];
  const float* fW3 = (const float*)d_in[18]; const float* fb3 = (const float*)d_in[19];
  float* out = (float*)d_out;

  const int n  = in_sizes[0] / 4;  // N = 30000
  const int nE = in_sizes[1];      // E = 480000

  // workspace (~48 MB):
  // ansc0 bf16[n*64] | ans1 f32[n*64] | ansc1 bf16[n*64] | ansc2 bf16[n*64]
  // | T f32[n*18] | Xb u16[n*64] | W1T | W2T | W0T | WT3 | BIA
  // | jw[n*48] | cnt[n] | jwB[n*128] | cnt8[n*8]
  unsigned short* ansc0 = (unsigned short*)d_ws;
  float*          ans1  = (float*)(ansc0 + (size_t)n * 64);
  unsigned short* ansc1 = (unsigned short*)(ans1 + (size_t)n * 64);
  unsigned short* ansc2 = ansc1 + (size_t)n * 64;
  float*          T     = (float*)(ansc2 + (size_t)n * 64);
  unsigned short* Xb16  = (unsigned short*)(T + (size_t)n * 18);
  short* W1T = (short*)(Xb16 + (size_t)n * 64);
  short* W2T = W1T + 36864;
  short* W0T = W2T + 36864;
  short* WT3 = W0T + 36864;
  float* BIA = (float*)(WT3 + 1024);
  int*   jw   = (int*)(BIA + 192);
  int*   cnt  = jw + (size_t)n * CAP;
  int*   jwB  = cnt + n;
  int*   cnt8 = jwB + (size_t)n * 128;

  hipMemsetAsync(cnt8, 0, (size_t)n * 8 * sizeof(int), stream);
  const int fillBlocks = (nE + 255) / 256;
  const int prepBlocks = (111808 + 255) / 256;
  const int xbBlocks   = (n * 8 + 255) / 256;
  fill_prep<<<fillBlocks + prepBlocks + xbBlocks, 256, 0, stream>>>(
      dist, fi, fj, cnt8, jwB, nE,
      cW0, fW0, cb0, fb0, cW1, fW1, cb1, fb1, cW2, fW2, cb2, fb2, cW3,
      W0T, W1T, W2T, WT3, BIA, X, Xb16, n, fillBlocks, prepBlocks);

  // sort/compact: buckets -> jw + exact cnt
  compact_kernel<<<(n + 3) / 4, 256, 0, stream>>>(jwB, cnt8, jw, cnt, n);

  const int nodeBlocks = (n + 15) / 16;
  // layer0: conv_agg on padded Xb with W0T (flags=0)
  conv_agg<<<nodeBlocks, 1024, 0, stream>>>(Xb16, cnt, jw, W0T, BIA,
                                            ans1, ans1, ansc0, WT3, T, 0, n);
  // conv1: ansc0 -> ans1 (fp32) + ansc1 (flags=2)
  conv_agg<<<nodeBlocks, 1024, 0, stream>>>(ansc0, cnt, jw, W1T, BIA + 64,
                                            ans1, ans1, ansc1, WT3, T, 2, n);
  // conv2: ansc1 (+ans1 resid) -> ansc2 + T (flags=5)
  conv_agg<<<nodeBlocks, 1024, 0, stream>>>(ansc1, cnt, jw, W2T, BIA + 128,
                                            ans1, ans1, ansc2, WT3, T, 5, n);
  // layer3
  layer3_kernel<<<(n * 64 + 255) / 256, 256, 0, stream>>>(ansc2, T, cnt, jw,
                                                          cb3, fb3, fW3, out, n);
}